// Round 2
// baseline (859.327 us; speedup 1.0000x reference)
//
#include <hip/hip_runtime.h>
#include <math.h>

#define N_NODES 100000
#define N_EDGES 1200000
#define DIM 64
#define TDIM 32
#define NLAYERS 3
#define NGRAPH 500
#define NP (N_NODES + 1)
#define NB_SCAN ((NP + 255) / 256)   // 391

// ---------------- setup kernels ----------------

__global__ __launch_bounds__(512) void k_graph_start(const int* __restrict__ gid,
                                                     int* __restrict__ gstart,
                                                     float* __restrict__ inv_safe) {
    int t = threadIdx.x;
    if (t <= NGRAPH) {
        int lo = 0, hi = N_NODES;
        while (lo < hi) {
            int mid = (lo + hi) >> 1;
            if (gid[mid] < t) lo = mid + 1; else hi = mid;
        }
        gstart[t] = lo;
    }
    __syncthreads();
    if (t < NGRAPH) {
        int c = gstart[t + 1] - gstart[t];
        inv_safe[t] = 1.0f / (float)(c > 1 ? c : 1);
    }
}

__global__ __launch_bounds__(256) void k_hist(const int* __restrict__ dst, int* __restrict__ deg) {
    int e = blockIdx.x * 256 + threadIdx.x;
    if (e < N_EDGES) atomicAdd(&deg[dst[e]], 1);
}

__global__ __launch_bounds__(256) void k_scanA(const int* __restrict__ deg, int* __restrict__ bsum) {
    __shared__ int s[256];
    int t = threadIdx.x;
    int i = blockIdx.x * 256 + t;
    s[t] = (i < NP) ? deg[i] : 0;
    __syncthreads();
    for (int off = 128; off > 0; off >>= 1) {
        if (t < off) s[t] += s[t + off];
        __syncthreads();
    }
    if (t == 0) bsum[blockIdx.x] = s[0];
}

__global__ __launch_bounds__(512) void k_scanB(const int* __restrict__ bsum, int* __restrict__ boff) {
    __shared__ int s[512];
    int t = threadIdx.x;
    s[t] = (t < NB_SCAN) ? bsum[t] : 0;
    __syncthreads();
    for (int off = 1; off < 512; off <<= 1) {
        int v = (t >= off) ? s[t - off] : 0;
        __syncthreads();
        s[t] += v;
        __syncthreads();
    }
    if (t < NB_SCAN) boff[t] = t ? s[t - 1] : 0;
}

__global__ __launch_bounds__(256) void k_scanC(const int* __restrict__ deg, const int* __restrict__ boff,
                                               int* __restrict__ offs) {
    __shared__ int s[256];
    int t = threadIdx.x;
    int i = blockIdx.x * 256 + t;
    int v = (i < NP) ? deg[i] : 0;
    s[t] = v;
    __syncthreads();
    for (int off = 1; off < 256; off <<= 1) {
        int u = (t >= off) ? s[t - off] : 0;
        __syncthreads();
        s[t] += u;
        __syncthreads();
    }
    if (i < NP) offs[i] = boff[blockIdx.x] + s[t] - v;  // exclusive scan
}

__global__ __launch_bounds__(256) void k_cursor(const int* __restrict__ offs, int* __restrict__ cur) {
    int i = blockIdx.x * 256 + threadIdx.x;
    if (i < N_NODES) cur[i] = offs[i];
}

__global__ __launch_bounds__(256) void k_fill(const int* __restrict__ src, const int* __restrict__ dst,
                                              int* __restrict__ cur, int* __restrict__ csr) {
    int e = blockIdx.x * 256 + threadIdx.x;
    if (e < N_EDGES) {
        int d = dst[e];
        int p = atomicAdd(&cur[d], 1);
        csr[p] = src[e];
    }
}

// ---------------- per-layer: aggregation (GINConv input) ----------------
__global__ __launch_bounds__(256) void k_agg(const float* __restrict__ feat, const int* __restrict__ offs,
                                             const int* __restrict__ csr, const float* __restrict__ eps,
                                             int l, float* __restrict__ hin) {
    int w = threadIdx.x >> 6;
    int lane = threadIdx.x & 63;
    int node = blockIdx.x * 4 + w;
    if (node >= N_NODES) return;
    int e0 = offs[node], e1 = offs[node + 1];
    float acc = 0.f;
    for (int e = e0; e < e1; e += 4) {
        int eL = e1 - 1;
        int i1 = (e + 1 < eL) ? e + 1 : eL;
        int i2 = (e + 2 < eL) ? e + 2 : eL;
        int i3 = (e + 3 < eL) ? e + 3 : eL;
        int s0 = csr[e], s1 = csr[i1], s2 = csr[i2], s3 = csr[i3];
        float v0 = feat[s0 * DIM + lane];
        float v1 = (e + 1 <= eL) ? feat[s1 * DIM + lane] : 0.f;
        float v2 = (e + 2 <= eL) ? feat[s2 * DIM + lane] : 0.f;
        float v3 = (e + 3 <= eL) ? feat[s3 * DIM + lane] : 0.f;
        acc += (v0 + v1) + (v2 + v3);
    }
    float ep = 1.0f + eps[l];
    hin[node * DIM + lane] = ep * feat[node * DIM + lane] + acc;
}

// ---------------- per-layer: conv MLP  h = relu(hin@W1+b1)@W2+b2 ----------------
__global__ __launch_bounds__(256) void k_mlp(const float* __restrict__ hin,
                                             const float* __restrict__ w1, const float* __restrict__ b1,
                                             const float* __restrict__ w2, const float* __restrict__ b2,
                                             float* __restrict__ hout) {
    __shared__ __align__(16) float sW1[64 * 64];
    __shared__ __align__(16) float sW2[64 * 64];
    __shared__ __align__(16) float sIn[64 * 68];
    __shared__ __align__(16) float sT[64 * 68];
    __shared__ float sB1[64], sB2[64];
    int t = threadIdx.x;
    int row0 = blockIdx.x * 64;
#pragma unroll
    for (int i = 0; i < 16; i++) {
        sW1[i * 256 + t] = w1[i * 256 + t];
        sW2[i * 256 + t] = w2[i * 256 + t];
    }
    if (t < 64) { sB1[t] = b1[t]; sB2[t] = b2[t]; }
#pragma unroll
    for (int i = 0; i < 16; i++) {
        int idx = i * 256 + t;
        int r = idx >> 6, c = idx & 63;
        int row = row0 + r;
        sIn[r * 68 + c] = (row < N_NODES) ? hin[row * 64 + c] : 0.f;
    }
    __syncthreads();

    int c0 = (t & 15) * 4;
    int r0 = (t >> 4) * 4;
    float acc[4][4];
#pragma unroll
    for (int i = 0; i < 4; i++)
#pragma unroll
        for (int j = 0; j < 4; j++) acc[i][j] = sB1[c0 + j];
#pragma unroll 4
    for (int k = 0; k < 64; k++) {
        float4 w = *(const float4*)&sW1[k * 64 + c0];
#pragma unroll
        for (int i = 0; i < 4; i++) {
            float a = sIn[(r0 + i) * 68 + k];
            acc[i][0] += a * w.x; acc[i][1] += a * w.y;
            acc[i][2] += a * w.z; acc[i][3] += a * w.w;
        }
    }
#pragma unroll
    for (int i = 0; i < 4; i++)
#pragma unroll
        for (int j = 0; j < 4; j++)
            sT[(r0 + i) * 68 + c0 + j] = fmaxf(acc[i][j], 0.f);
    __syncthreads();

    float acc2[4][4];
#pragma unroll
    for (int i = 0; i < 4; i++)
#pragma unroll
        for (int j = 0; j < 4; j++) acc2[i][j] = sB2[c0 + j];
#pragma unroll 4
    for (int k = 0; k < 64; k++) {
        float4 w = *(const float4*)&sW2[k * 64 + c0];
#pragma unroll
        for (int i = 0; i < 4; i++) {
            float a = sT[(r0 + i) * 68 + k];
            acc2[i][0] += a * w.x; acc2[i][1] += a * w.y;
            acc2[i][2] += a * w.z; acc2[i][3] += a * w.w;
        }
    }
#pragma unroll
    for (int i = 0; i < 4; i++) {
        int row = row0 + r0 + i;
        if (row < N_NODES) {
            float4 o; o.x = acc2[i][0]; o.y = acc2[i][1]; o.z = acc2[i][2]; o.w = acc2[i][3];
            *(float4*)&hout[row * 64 + c0] = o;
        }
    }
}

// ---------------- per-layer: per-graph GraphNorm stats (single pass) ----------------
// gms[g][c] = mean*scale ; gcoef[g][c] = gnw * rsqrt(var + 1e-8)
// Also pre-writes proj bias pb2 into out (covers d_out poison).
__global__ __launch_bounds__(256) void k_stats(const float* __restrict__ h,
                                               const int* __restrict__ gstart,
                                               const float* __restrict__ inv_safe,
                                               const float* __restrict__ gnw, const float* __restrict__ gns,
                                               const float* __restrict__ pb2,
                                               float* __restrict__ gms, float* __restrict__ gcoef,
                                               float* __restrict__ out, int l) {
    __shared__ float sRS[4][64];
    __shared__ float sRQ[4][64];
    int t = threadIdx.x;
    int g = blockIdx.x;
    int s = gstart[g], e = gstart[g + 1];
    int nn = e - s;
    float inv = inv_safe[g];
    int lane = t & 63, q = t >> 6;
    float sum = 0.f, sumsq = 0.f;
    for (int i = s + q; i < e; i += 4) {
        float v = h[i * 64 + lane];
        sum += v;
        sumsq += v * v;
    }
    sRS[q][lane] = sum;
    sRQ[q][lane] = sumsq;
    __syncthreads();
    if (t < 64) {
        float S = sRS[0][t] + sRS[1][t] + sRS[2][t] + sRS[3][t];
        float Q = sRQ[0][t] + sRQ[1][t] + sRQ[2][t] + sRQ[3][t];
        float m = S * inv;
        float ms = m * gns[t];
        float var = (Q - 2.f * ms * S + (float)nn * ms * ms) * inv;
        gms[g * 64 + t] = ms;
        gcoef[g * 64 + t] = gnw[t] * rsqrtf(var + 1e-8f);
    }
    if (t < TDIM) {
        out[g * (NLAYERS * TDIM) + l * TDIM + t] = (nn > 0) ? pb2[t] : 0.f;
    }
}

// ---------------- per-layer: apply norm+relu, proj MLP, segmented pooling ----------------
// node-parallel, 64-row tiles
__global__ __launch_bounds__(256) void k_apply_proj(const float* __restrict__ h,
                                                    const int* __restrict__ gid,
                                                    const float* __restrict__ gms,
                                                    const float* __restrict__ gcoef,
                                                    const float* __restrict__ gnb,
                                                    const float* __restrict__ inv_safe,
                                                    const float* __restrict__ p1, const float* __restrict__ pb1,
                                                    const float* __restrict__ p2,
                                                    float* __restrict__ feat, float* __restrict__ out, int l) {
    __shared__ __align__(16) float sP1[64 * 64];
    __shared__ __align__(16) float sP2[64 * 32];
    __shared__ __align__(16) float sFeat[64 * 68];   // first 64*32 floats reused as sZ
    __shared__ __align__(16) float sM[64 * 68];
    __shared__ float sPB1[64], sGnB[64];
    __shared__ int sGid[64];
    float* sZ = sFeat;  // alias, stride 32; safe after GEMM1 completes

    int t = threadIdx.x;
    int row0 = blockIdx.x * 64;
#pragma unroll
    for (int i = 0; i < 16; i++) sP1[i * 256 + t] = p1[i * 256 + t];
#pragma unroll
    for (int i = 0; i < 8; i++) sP2[i * 256 + t] = p2[i * 256 + t];
    if (t < 64) {
        sPB1[t] = pb1[t];
        sGnB[t] = gnb[t];
        int row = row0 + t;
        sGid[t] = (row < N_NODES) ? gid[row] : -1;
    }

    // stage tile: apply GraphNorm + relu, write next-layer feat
#pragma unroll
    for (int i = 0; i < 16; i++) {
        int idx = i * 256 + t;
        int r = idx >> 6, c = idx & 63;
        int row = row0 + r;
        float val = 0.f;
        if (row < N_NODES) {
            int g = gid[row];
            float ms = gms[g * 64 + c];
            float coef = gcoef[g * 64 + c];
            val = fmaxf(coef * (h[row * 64 + c] - ms) + gnb[c], 0.f);
            feat[row * 64 + c] = val;
        }
        sFeat[r * 68 + c] = val;
    }
    __syncthreads();

    // GEMM1: t_mid = relu(sFeat @ P1 + pb1)
    int c0 = (t & 15) * 4;
    int r0 = (t >> 4) * 4;
    float acc[4][4];
#pragma unroll
    for (int i = 0; i < 4; i++)
#pragma unroll
        for (int j = 0; j < 4; j++) acc[i][j] = sPB1[c0 + j];
#pragma unroll 4
    for (int k = 0; k < 64; k++) {
        float4 w = *(const float4*)&sP1[k * 64 + c0];
#pragma unroll
        for (int i = 0; i < 4; i++) {
            float a = sFeat[(r0 + i) * 68 + k];
            acc[i][0] += a * w.x; acc[i][1] += a * w.y;
            acc[i][2] += a * w.z; acc[i][3] += a * w.w;
        }
    }
#pragma unroll
    for (int i = 0; i < 4; i++)
#pragma unroll
        for (int j = 0; j < 4; j++)
            sM[(r0 + i) * 68 + c0 + j] = fmaxf(acc[i][j], 0.f);
    __syncthreads();

    // GEMM2: z = t_mid @ P2 (bias handled in k_stats), 2 rows x 4 cols per thread
    int r2 = (t >> 3) * 2;
    int cz = (t & 7) * 4;
    float z0[4] = {0.f, 0.f, 0.f, 0.f};
    float z1[4] = {0.f, 0.f, 0.f, 0.f};
#pragma unroll 4
    for (int k = 0; k < 64; k++) {
        float4 w = *(const float4*)&sP2[k * 32 + cz];
        float x0 = sM[r2 * 68 + k];
        float x1 = sM[(r2 + 1) * 68 + k];
        z0[0] += x0 * w.x; z0[1] += x0 * w.y; z0[2] += x0 * w.z; z0[3] += x0 * w.w;
        z1[0] += x1 * w.x; z1[1] += x1 * w.y; z1[2] += x1 * w.z; z1[3] += x1 * w.w;
    }
    // sFeat reads all done (GEMM1 ended at previous barrier) -> safe to write sZ alias
#pragma unroll
    for (int j = 0; j < 4; j++) {
        sZ[r2 * 32 + cz + j] = z0[j];
        sZ[(r2 + 1) * 32 + cz + j] = z1[j];
    }
    __syncthreads();

    // segmented pooling: 32 threads, one per output column, walk 64 rows
    if (t < 32) {
        int cur = sGid[0];
        float a = 0.f;
        for (int r = 0; r < 64; r++) {
            int g = sGid[r];
            if (g != cur) {
                if (cur >= 0) atomicAdd(&out[cur * (NLAYERS * TDIM) + l * TDIM + t], a * inv_safe[cur]);
                cur = g;
                a = 0.f;
            }
            if (g >= 0) a += sZ[r * 32 + t];
        }
        if (cur >= 0) atomicAdd(&out[cur * (NLAYERS * TDIM) + l * TDIM + t], a * inv_safe[cur]);
    }
}

// ---------------- launcher ----------------

extern "C" void kernel_launch(void* const* d_in, const int* in_sizes, int n_in,
                              void* d_out, int out_size, void* d_ws, size_t ws_size,
                              hipStream_t stream) {
    const float* x        = (const float*)d_in[0];
    const int*   src      = (const int*)d_in[1];
    const int*   dst      = (const int*)d_in[2];
    const int*   gid      = (const int*)d_in[3];
    const float* eps      = (const float*)d_in[4];
    const float* conv_w1  = (const float*)d_in[5];
    const float* conv_b1  = (const float*)d_in[6];
    const float* conv_w2  = (const float*)d_in[7];
    const float* conv_b2  = (const float*)d_in[8];
    const float* gn_w     = (const float*)d_in[9];
    const float* gn_b     = (const float*)d_in[10];
    const float* gn_s     = (const float*)d_in[11];
    const float* proj_w1  = (const float*)d_in[12];
    const float* proj_b1  = (const float*)d_in[13];
    const float* proj_w2  = (const float*)d_in[14];
    const float* proj_b2  = (const float*)d_in[15];
    float* out = (float*)d_out;

    char* ws = (char*)d_ws;
    size_t off = 0;
    auto alloc = [&](size_t bytes) { char* p = ws + off; off += (bytes + 255) & ~(size_t)255; return p; };
    int*   offs     = (int*)alloc(NP * sizeof(int));
    int*   deg      = (int*)alloc(NP * sizeof(int));      // also reused as cursor
    int*   gstart   = (int*)alloc((NGRAPH + 1) * sizeof(int));
    float* inv_safe = (float*)alloc(NGRAPH * sizeof(float));
    int*   bsum     = (int*)alloc(NB_SCAN * sizeof(int));
    int*   boff     = (int*)alloc(NB_SCAN * sizeof(int));
    int*   csr      = (int*)alloc(N_EDGES * sizeof(int));
    float* hin      = (float*)alloc((size_t)N_NODES * DIM * sizeof(float));
    float* hbuf     = (float*)alloc((size_t)N_NODES * DIM * sizeof(float));
    float* featbuf  = (float*)alloc((size_t)N_NODES * DIM * sizeof(float));
    float* gms      = (float*)alloc((size_t)NGRAPH * 64 * sizeof(float));
    float* gcoef    = (float*)alloc((size_t)NGRAPH * 64 * sizeof(float));

    // setup
    k_graph_start<<<1, 512, 0, stream>>>(gid, gstart, inv_safe);
    hipMemsetAsync(deg, 0, NP * sizeof(int), stream);
    int ebl = (N_EDGES + 255) / 256;
    k_hist<<<ebl, 256, 0, stream>>>(dst, deg);
    k_scanA<<<NB_SCAN, 256, 0, stream>>>(deg, bsum);
    k_scanB<<<1, 512, 0, stream>>>(bsum, boff);
    k_scanC<<<NB_SCAN, 256, 0, stream>>>(deg, boff, offs);
    k_cursor<<<NB_SCAN, 256, 0, stream>>>(offs, deg);   // deg becomes cursor
    k_fill<<<ebl, 256, 0, stream>>>(src, dst, deg, csr);

    int aggbl = (N_NODES + 3) / 4;
    int mlpbl = (N_NODES + 63) / 64;
    for (int l = 0; l < NLAYERS; l++) {
        const float* fin = (l == 0) ? x : featbuf;
        k_agg<<<aggbl, 256, 0, stream>>>(fin, offs, csr, eps, l, hin);
        k_mlp<<<mlpbl, 256, 0, stream>>>(hin, conv_w1 + l * 4096, conv_b1 + l * 64,
                                         conv_w2 + l * 4096, conv_b2 + l * 64, hbuf);
        k_stats<<<NGRAPH, 256, 0, stream>>>(hbuf, gstart, inv_safe,
                                            gn_w + l * 64, gn_s + l * 64, proj_b2 + l * 32,
                                            gms, gcoef, out, l);
        k_apply_proj<<<mlpbl, 256, 0, stream>>>(hbuf, gid, gms, gcoef, gn_b + l * 64,
                                                inv_safe, proj_w1 + l * 4096, proj_b1 + l * 64,
                                                proj_w2 + l * 2048, featbuf, out, l);
    }
}

// Round 3
// 769.188 us; speedup vs baseline: 1.1172x; 1.1172x over previous
//
#include <hip/hip_runtime.h>
#include <math.h>

#define N_NODES 100000
#define N_EDGES 1200000
#define DIM 64
#define TDIM 32
#define NLAYERS 3
#define NGRAPH 500
#define NP (N_NODES + 1)

#define BUCKW 512                      // nodes per bucket (dst >> 9)
#define NBUCK ((N_NODES + BUCKW - 1) / BUCKW)   // 196
#define ECHUNK ((N_EDGES + 255) / 256)          // 4688 edges per block (256 blocks)

// ---------------- setup: graph ranges ----------------

__global__ __launch_bounds__(512) void k_graph_start(const int* __restrict__ gid,
                                                     int* __restrict__ gstart,
                                                     float* __restrict__ inv_safe) {
    int t = threadIdx.x;
    if (t <= NGRAPH) {
        int lo = 0, hi = N_NODES;
        while (lo < hi) {
            int mid = (lo + hi) >> 1;
            if (gid[mid] < t) lo = mid + 1; else hi = mid;
        }
        gstart[t] = lo;
    }
    __syncthreads();
    if (t < NGRAPH) {
        int c = gstart[t + 1] - gstart[t];
        inv_safe[t] = 1.0f / (float)(c > 1 ? c : 1);
    }
}

// ---------------- setup: bucketed CSR build ----------------
// Pass 1: bucket histogram (bucket = dst >> 9)
__global__ __launch_bounds__(256) void k_bhist(const int* __restrict__ dst, int* __restrict__ bcnt) {
    __shared__ int h[NBUCK];
    int t = threadIdx.x;
    for (int i = t; i < NBUCK; i += 256) h[i] = 0;
    __syncthreads();
    int e0 = blockIdx.x * ECHUNK;
    int e1 = e0 + ECHUNK; if (e1 > N_EDGES) e1 = N_EDGES;
    for (int e = e0 + t; e < e1; e += 256) atomicAdd(&h[dst[e] >> 9], 1);
    __syncthreads();
    for (int i = t; i < NBUCK; i += 256) if (h[i]) atomicAdd(&bcnt[i], h[i]);
}

// Pass 2: scan bucket counts -> bases + cursors
__global__ __launch_bounds__(256) void k_bscan(const int* __restrict__ bcnt,
                                               int* __restrict__ bbase, int* __restrict__ bcursor) {
    __shared__ int s[256];
    int t = threadIdx.x;
    s[t] = (t < NBUCK) ? bcnt[t] : 0;
    __syncthreads();
    for (int off = 1; off < 256; off <<= 1) {
        int v = (t >= off) ? s[t - off] : 0;
        __syncthreads();
        s[t] += v;
        __syncthreads();
    }
    int ex = t ? s[t - 1] : 0;
    if (t < NBUCK) { bbase[t] = ex; bcursor[t] = ex; }
    if (t == 0) bbase[NBUCK] = N_EDGES;
}

// Pass 3: scatter (src,dst) pairs grouped by bucket
__global__ __launch_bounds__(256) void k_bscatter(const int* __restrict__ src, const int* __restrict__ dst,
                                                  int* __restrict__ bcursor, int2* __restrict__ ebuf) {
    __shared__ int cnt[NBUCK];
    __shared__ int base[NBUCK];
    int t = threadIdx.x;
    for (int i = t; i < NBUCK; i += 256) cnt[i] = 0;
    __syncthreads();
    int e0 = blockIdx.x * ECHUNK;
    int e1 = e0 + ECHUNK; if (e1 > N_EDGES) e1 = N_EDGES;
    for (int e = e0 + t; e < e1; e += 256) atomicAdd(&cnt[dst[e] >> 9], 1);
    __syncthreads();
    for (int i = t; i < NBUCK; i += 256) base[i] = cnt[i] ? atomicAdd(&bcursor[i], cnt[i]) : 0;
    __syncthreads();
    for (int i = t; i < NBUCK; i += 256) cnt[i] = 0;
    __syncthreads();
    for (int e = e0 + t; e < e1; e += 256) {
        int d = dst[e];
        int b = d >> 9;
        int r = atomicAdd(&cnt[b], 1);
        ebuf[base[b] + r] = make_int2(src[e], d);
    }
}

// Pass 4: per-bucket CSR (one block per bucket; all scatters in LDS / own L2 segment)
__global__ __launch_bounds__(256) void k_bcsr(const int2* __restrict__ ebuf, const int* __restrict__ bbase,
                                              int* __restrict__ offs, int* __restrict__ csr) {
    __shared__ int ldeg[BUCKW];
    __shared__ int lscan[BUCKW];
    __shared__ int lcur[BUCKW];
    int t = threadIdx.x;
    int b = blockIdx.x;
    int nbase = b << 9;
    int ebeg = bbase[b], eend = bbase[b + 1];
    ldeg[t] = 0; ldeg[t + 256] = 0;
    __syncthreads();
    for (int e = ebeg + t; e < eend; e += 256) atomicAdd(&ldeg[ebuf[e].y - nbase], 1);
    __syncthreads();
    lscan[t] = ldeg[t]; lscan[t + 256] = ldeg[t + 256];
    __syncthreads();
    for (int off = 1; off < BUCKW; off <<= 1) {
        int i0 = t, i1 = t + 256;
        int v0 = (i0 >= off) ? lscan[i0 - off] : 0;
        int v1 = (i1 >= off) ? lscan[i1 - off] : 0;
        __syncthreads();
        lscan[i0] += v0; lscan[i1] += v1;
        __syncthreads();
    }
    int ex0 = lscan[t] - ldeg[t];
    int ex1 = lscan[t + 256] - ldeg[t + 256];
    lcur[t] = ex0; lcur[t + 256] = ex1;
    int n0 = nbase + t, n1 = nbase + t + 256;
    if (n0 < N_NODES) offs[n0] = ebeg + ex0;
    if (n1 < N_NODES) offs[n1] = ebeg + ex1;
    if (b == 0 && t == 0) offs[N_NODES] = N_EDGES;
    __syncthreads();
    for (int e = ebeg + t; e < eend; e += 256) {
        int2 p = ebuf[e];
        int slot = atomicAdd(&lcur[p.y - nbase], 1);
        csr[ebeg + slot] = p.x;
    }
}

// ---------------- per-layer: aggregation (GINConv input) ----------------
__global__ __launch_bounds__(256) void k_agg(const float* __restrict__ feat, const int* __restrict__ offs,
                                             const int* __restrict__ csr, const float* __restrict__ eps,
                                             int l, float* __restrict__ hin) {
    int w = threadIdx.x >> 6;
    int lane = threadIdx.x & 63;
    int node = blockIdx.x * 4 + w;
    if (node >= N_NODES) return;
    int e0 = offs[node], e1 = offs[node + 1];
    float acc = 0.f;
    for (int e = e0; e < e1; e += 4) {
        int eL = e1 - 1;
        int i1 = (e + 1 < eL) ? e + 1 : eL;
        int i2 = (e + 2 < eL) ? e + 2 : eL;
        int i3 = (e + 3 < eL) ? e + 3 : eL;
        int s0 = csr[e], s1 = csr[i1], s2 = csr[i2], s3 = csr[i3];
        float v0 = feat[s0 * DIM + lane];
        float v1 = (e + 1 <= eL) ? feat[s1 * DIM + lane] : 0.f;
        float v2 = (e + 2 <= eL) ? feat[s2 * DIM + lane] : 0.f;
        float v3 = (e + 3 <= eL) ? feat[s3 * DIM + lane] : 0.f;
        acc += (v0 + v1) + (v2 + v3);
    }
    float ep = 1.0f + eps[l];
    hin[node * DIM + lane] = ep * feat[node * DIM + lane] + acc;
}

// ---------------- per-layer: conv MLP  h = relu(hin@W1+b1)@W2+b2 ----------------
__global__ __launch_bounds__(256) void k_mlp(const float* __restrict__ hin,
                                             const float* __restrict__ w1, const float* __restrict__ b1,
                                             const float* __restrict__ w2, const float* __restrict__ b2,
                                             float* __restrict__ hout) {
    __shared__ __align__(16) float sW1[64 * 64];
    __shared__ __align__(16) float sW2[64 * 64];
    __shared__ __align__(16) float sIn[64 * 68];
    __shared__ __align__(16) float sT[64 * 68];
    __shared__ float sB1[64], sB2[64];
    int t = threadIdx.x;
    int row0 = blockIdx.x * 64;
#pragma unroll
    for (int i = 0; i < 16; i++) {
        sW1[i * 256 + t] = w1[i * 256 + t];
        sW2[i * 256 + t] = w2[i * 256 + t];
    }
    if (t < 64) { sB1[t] = b1[t]; sB2[t] = b2[t]; }
#pragma unroll
    for (int i = 0; i < 16; i++) {
        int idx = i * 256 + t;
        int r = idx >> 6, c = idx & 63;
        int row = row0 + r;
        sIn[r * 68 + c] = (row < N_NODES) ? hin[row * 64 + c] : 0.f;
    }
    __syncthreads();

    int c0 = (t & 15) * 4;
    int r0 = (t >> 4) * 4;
    float acc[4][4];
#pragma unroll
    for (int i = 0; i < 4; i++)
#pragma unroll
        for (int j = 0; j < 4; j++) acc[i][j] = sB1[c0 + j];
#pragma unroll 4
    for (int k = 0; k < 64; k++) {
        float4 w = *(const float4*)&sW1[k * 64 + c0];
#pragma unroll
        for (int i = 0; i < 4; i++) {
            float a = sIn[(r0 + i) * 68 + k];
            acc[i][0] += a * w.x; acc[i][1] += a * w.y;
            acc[i][2] += a * w.z; acc[i][3] += a * w.w;
        }
    }
#pragma unroll
    for (int i = 0; i < 4; i++)
#pragma unroll
        for (int j = 0; j < 4; j++)
            sT[(r0 + i) * 68 + c0 + j] = fmaxf(acc[i][j], 0.f);
    __syncthreads();

    float acc2[4][4];
#pragma unroll
    for (int i = 0; i < 4; i++)
#pragma unroll
        for (int j = 0; j < 4; j++) acc2[i][j] = sB2[c0 + j];
#pragma unroll 4
    for (int k = 0; k < 64; k++) {
        float4 w = *(const float4*)&sW2[k * 64 + c0];
#pragma unroll
        for (int i = 0; i < 4; i++) {
            float a = sT[(r0 + i) * 68 + k];
            acc2[i][0] += a * w.x; acc2[i][1] += a * w.y;
            acc2[i][2] += a * w.z; acc2[i][3] += a * w.w;
        }
    }
#pragma unroll
    for (int i = 0; i < 4; i++) {
        int row = row0 + r0 + i;
        if (row < N_NODES) {
            float4 o; o.x = acc2[i][0]; o.y = acc2[i][1]; o.z = acc2[i][2]; o.w = acc2[i][3];
            *(float4*)&hout[row * 64 + c0] = o;
        }
    }
}

// ---------------- per-layer: per-graph GraphNorm stats ----------------
__global__ __launch_bounds__(256) void k_stats(const float* __restrict__ h,
                                               const int* __restrict__ gstart,
                                               const float* __restrict__ inv_safe,
                                               const float* __restrict__ gnw, const float* __restrict__ gns,
                                               const float* __restrict__ pb2,
                                               float* __restrict__ gms, float* __restrict__ gcoef,
                                               float* __restrict__ out, int l) {
    __shared__ float sRS[4][64];
    __shared__ float sRQ[4][64];
    int t = threadIdx.x;
    int g = blockIdx.x;
    int s = gstart[g], e = gstart[g + 1];
    int nn = e - s;
    float inv = inv_safe[g];
    int lane = t & 63, q = t >> 6;
    float sum = 0.f, sumsq = 0.f;
    for (int i = s + q; i < e; i += 4) {
        float v = h[i * 64 + lane];
        sum += v;
        sumsq += v * v;
    }
    sRS[q][lane] = sum;
    sRQ[q][lane] = sumsq;
    __syncthreads();
    if (t < 64) {
        float S = sRS[0][t] + sRS[1][t] + sRS[2][t] + sRS[3][t];
        float Q = sRQ[0][t] + sRQ[1][t] + sRQ[2][t] + sRQ[3][t];
        float m = S * inv;
        float ms = m * gns[t];
        float var = (Q - 2.f * ms * S + (float)nn * ms * ms) * inv;
        gms[g * 64 + t] = ms;
        gcoef[g * 64 + t] = gnw[t] * rsqrtf(var + 1e-8f);
    }
    if (t < TDIM) {
        out[g * (NLAYERS * TDIM) + l * TDIM + t] = (nn > 0) ? pb2[t] : 0.f;
    }
}

// ---------------- per-layer: apply norm+relu, proj MLP, segmented pooling ----------------
__global__ __launch_bounds__(256) void k_apply_proj(const float* __restrict__ h,
                                                    const int* __restrict__ gid,
                                                    const float* __restrict__ gms,
                                                    const float* __restrict__ gcoef,
                                                    const float* __restrict__ gnb,
                                                    const float* __restrict__ inv_safe,
                                                    const float* __restrict__ p1, const float* __restrict__ pb1,
                                                    const float* __restrict__ p2,
                                                    float* __restrict__ feat, float* __restrict__ out, int l) {
    __shared__ __align__(16) float sP1[64 * 64];
    __shared__ __align__(16) float sP2[64 * 32];
    __shared__ __align__(16) float sFeat[64 * 68];   // first 64*32 floats reused as sZ
    __shared__ __align__(16) float sM[64 * 68];
    __shared__ float sPB1[64], sGnB[64];
    __shared__ int sGid[64];
    float* sZ = sFeat;  // alias, stride 32; safe after GEMM1 completes

    int t = threadIdx.x;
    int row0 = blockIdx.x * 64;
#pragma unroll
    for (int i = 0; i < 16; i++) sP1[i * 256 + t] = p1[i * 256 + t];
#pragma unroll
    for (int i = 0; i < 8; i++) sP2[i * 256 + t] = p2[i * 256 + t];
    if (t < 64) {
        sPB1[t] = pb1[t];
        sGnB[t] = gnb[t];
        int row = row0 + t;
        sGid[t] = (row < N_NODES) ? gid[row] : -1;
    }

#pragma unroll
    for (int i = 0; i < 16; i++) {
        int idx = i * 256 + t;
        int r = idx >> 6, c = idx & 63;
        int row = row0 + r;
        float val = 0.f;
        if (row < N_NODES) {
            int g = gid[row];
            float ms = gms[g * 64 + c];
            float coef = gcoef[g * 64 + c];
            val = fmaxf(coef * (h[row * 64 + c] - ms) + gnb[c], 0.f);
            feat[row * 64 + c] = val;
        }
        sFeat[r * 68 + c] = val;
    }
    __syncthreads();

    int c0 = (t & 15) * 4;
    int r0 = (t >> 4) * 4;
    float acc[4][4];
#pragma unroll
    for (int i = 0; i < 4; i++)
#pragma unroll
        for (int j = 0; j < 4; j++) acc[i][j] = sPB1[c0 + j];
#pragma unroll 4
    for (int k = 0; k < 64; k++) {
        float4 w = *(const float4*)&sP1[k * 64 + c0];
#pragma unroll
        for (int i = 0; i < 4; i++) {
            float a = sFeat[(r0 + i) * 68 + k];
            acc[i][0] += a * w.x; acc[i][1] += a * w.y;
            acc[i][2] += a * w.z; acc[i][3] += a * w.w;
        }
    }
#pragma unroll
    for (int i = 0; i < 4; i++)
#pragma unroll
        for (int j = 0; j < 4; j++)
            sM[(r0 + i) * 68 + c0 + j] = fmaxf(acc[i][j], 0.f);
    __syncthreads();

    int r2 = (t >> 3) * 2;
    int cz = (t & 7) * 4;
    float z0[4] = {0.f, 0.f, 0.f, 0.f};
    float z1[4] = {0.f, 0.f, 0.f, 0.f};
#pragma unroll 4
    for (int k = 0; k < 64; k++) {
        float4 w = *(const float4*)&sP2[k * 32 + cz];
        float x0 = sM[r2 * 68 + k];
        float x1 = sM[(r2 + 1) * 68 + k];
        z0[0] += x0 * w.x; z0[1] += x0 * w.y; z0[2] += x0 * w.z; z0[3] += x0 * w.w;
        z1[0] += x1 * w.x; z1[1] += x1 * w.y; z1[2] += x1 * w.z; z1[3] += x1 * w.w;
    }
#pragma unroll
    for (int j = 0; j < 4; j++) {
        sZ[r2 * 32 + cz + j] = z0[j];
        sZ[(r2 + 1) * 32 + cz + j] = z1[j];
    }
    __syncthreads();

    if (t < 32) {
        int cur = sGid[0];
        float a = 0.f;
        for (int r = 0; r < 64; r++) {
            int g = sGid[r];
            if (g != cur) {
                if (cur >= 0) atomicAdd(&out[cur * (NLAYERS * TDIM) + l * TDIM + t], a * inv_safe[cur]);
                cur = g;
                a = 0.f;
            }
            if (g >= 0) a += sZ[r * 32 + t];
        }
        if (cur >= 0) atomicAdd(&out[cur * (NLAYERS * TDIM) + l * TDIM + t], a * inv_safe[cur]);
    }
}

// ---------------- launcher ----------------

extern "C" void kernel_launch(void* const* d_in, const int* in_sizes, int n_in,
                              void* d_out, int out_size, void* d_ws, size_t ws_size,
                              hipStream_t stream) {
    const float* x        = (const float*)d_in[0];
    const int*   src      = (const int*)d_in[1];
    const int*   dst      = (const int*)d_in[2];
    const int*   gid      = (const int*)d_in[3];
    const float* eps      = (const float*)d_in[4];
    const float* conv_w1  = (const float*)d_in[5];
    const float* conv_b1  = (const float*)d_in[6];
    const float* conv_w2  = (const float*)d_in[7];
    const float* conv_b2  = (const float*)d_in[8];
    const float* gn_w     = (const float*)d_in[9];
    const float* gn_b     = (const float*)d_in[10];
    const float* gn_s     = (const float*)d_in[11];
    const float* proj_w1  = (const float*)d_in[12];
    const float* proj_b1  = (const float*)d_in[13];
    const float* proj_w2  = (const float*)d_in[14];
    const float* proj_b2  = (const float*)d_in[15];
    float* out = (float*)d_out;

    char* ws = (char*)d_ws;
    size_t off = 0;
    auto alloc = [&](size_t bytes) { char* p = ws + off; off += (bytes + 255) & ~(size_t)255; return p; };
    int*   offs     = (int*)alloc(NP * sizeof(int));
    int*   gstart   = (int*)alloc((NGRAPH + 1) * sizeof(int));
    float* inv_safe = (float*)alloc(NGRAPH * sizeof(float));
    int*   bcnt     = (int*)alloc(NBUCK * sizeof(int));
    int*   bbase    = (int*)alloc((NBUCK + 1) * sizeof(int));
    int*   bcursor  = (int*)alloc(NBUCK * sizeof(int));
    int*   csr      = (int*)alloc(N_EDGES * sizeof(int));
    float* hin      = (float*)alloc((size_t)N_NODES * DIM * sizeof(float));
    float* hbuf     = (float*)alloc((size_t)N_NODES * DIM * sizeof(float));
    float* featbuf  = (float*)alloc((size_t)N_NODES * DIM * sizeof(float));
    float* gms      = (float*)alloc((size_t)NGRAPH * 64 * sizeof(float));
    float* gcoef    = (float*)alloc((size_t)NGRAPH * 64 * sizeof(float));
    int2*  ebuf     = (int2*)hin;   // overlay: setup-only, finished before k_agg writes hin

    // setup
    k_graph_start<<<1, 512, 0, stream>>>(gid, gstart, inv_safe);
    hipMemsetAsync(bcnt, 0, NBUCK * sizeof(int), stream);
    k_bhist<<<256, 256, 0, stream>>>(dst, bcnt);
    k_bscan<<<1, 256, 0, stream>>>(bcnt, bbase, bcursor);
    k_bscatter<<<256, 256, 0, stream>>>(src, dst, bcursor, ebuf);
    k_bcsr<<<NBUCK, 256, 0, stream>>>(ebuf, bbase, offs, csr);

    int aggbl = (N_NODES + 3) / 4;
    int mlpbl = (N_NODES + 63) / 64;
    for (int l = 0; l < NLAYERS; l++) {
        const float* fin = (l == 0) ? x : featbuf;
        k_agg<<<aggbl, 256, 0, stream>>>(fin, offs, csr, eps, l, hin);
        k_mlp<<<mlpbl, 256, 0, stream>>>(hin, conv_w1 + l * 4096, conv_b1 + l * 64,
                                         conv_w2 + l * 4096, conv_b2 + l * 64, hbuf);
        k_stats<<<NGRAPH, 256, 0, stream>>>(hbuf, gstart, inv_safe,
                                            gn_w + l * 64, gn_s + l * 64, proj_b2 + l * 32,
                                            gms, gcoef, out, l);
        k_apply_proj<<<mlpbl, 256, 0, stream>>>(hbuf, gid, gms, gcoef, gn_b + l * 64,
                                                inv_safe, proj_w1 + l * 4096, proj_b1 + l * 64,
                                                proj_w2 + l * 2048, featbuf, out, l);
    }
}

// Round 4
// 709.344 us; speedup vs baseline: 1.2114x; 1.0844x over previous
//
#include <hip/hip_runtime.h>
#include <math.h>

#define N_NODES 100000
#define N_EDGES 1200000
#define DIM 64
#define TDIM 32
#define NLAYERS 3
#define NGRAPH 500
#define NP (N_NODES + 1)

#define BUCKW 512                      // nodes per bucket (dst >> 9)
#define NBUCK ((N_NODES + BUCKW - 1) / BUCKW)   // 196
#define ECHUNK ((N_EDGES + 255) / 256)          // 4688 edges per block (256 blocks)

typedef unsigned short bfu;

__device__ __forceinline__ float bf2f(bfu u) {
    union { unsigned int i; float f; } v; v.i = ((unsigned int)u) << 16; return v.f;
}
__device__ __forceinline__ bfu f2bf(float f) {
    union { float f; unsigned int i; } v; v.f = f;
    unsigned int r = v.i + 0x7FFFu + ((v.i >> 16) & 1u);   // RNE
    return (bfu)(r >> 16);
}

// ---------------- setup: graph ranges ----------------

__global__ __launch_bounds__(512) void k_graph_start(const int* __restrict__ gid,
                                                     int* __restrict__ gstart,
                                                     float* __restrict__ inv_safe) {
    int t = threadIdx.x;
    if (t <= NGRAPH) {
        int lo = 0, hi = N_NODES;
        while (lo < hi) {
            int mid = (lo + hi) >> 1;
            if (gid[mid] < t) lo = mid + 1; else hi = mid;
        }
        gstart[t] = lo;
    }
    __syncthreads();
    if (t < NGRAPH) {
        int c = gstart[t + 1] - gstart[t];
        inv_safe[t] = 1.0f / (float)(c > 1 ? c : 1);
    }
}

// ---------------- setup: bucketed CSR build ----------------

__global__ __launch_bounds__(256) void k_bhist(const int* __restrict__ dst, int* __restrict__ bcnt) {
    __shared__ int h[NBUCK];
    int t = threadIdx.x;
    for (int i = t; i < NBUCK; i += 256) h[i] = 0;
    __syncthreads();
    int e0 = blockIdx.x * ECHUNK;
    int e1 = e0 + ECHUNK; if (e1 > N_EDGES) e1 = N_EDGES;
    for (int e = e0 + t; e < e1; e += 256) atomicAdd(&h[dst[e] >> 9], 1);
    __syncthreads();
    for (int i = t; i < NBUCK; i += 256) if (h[i]) atomicAdd(&bcnt[i], h[i]);
}

__global__ __launch_bounds__(256) void k_bscan(const int* __restrict__ bcnt,
                                               int* __restrict__ bbase, int* __restrict__ bcursor) {
    __shared__ int s[256];
    int t = threadIdx.x;
    s[t] = (t < NBUCK) ? bcnt[t] : 0;
    __syncthreads();
    for (int off = 1; off < 256; off <<= 1) {
        int v = (t >= off) ? s[t - off] : 0;
        __syncthreads();
        s[t] += v;
        __syncthreads();
    }
    int ex = t ? s[t - 1] : 0;
    if (t < NBUCK) { bbase[t] = ex; bcursor[t] = ex; }
    if (t == 0) bbase[NBUCK] = N_EDGES;
}

__global__ __launch_bounds__(256) void k_bscatter(const int* __restrict__ src, const int* __restrict__ dst,
                                                  int* __restrict__ bcursor, int2* __restrict__ ebuf) {
    __shared__ int cnt[NBUCK];
    __shared__ int base[NBUCK];
    int t = threadIdx.x;
    for (int i = t; i < NBUCK; i += 256) cnt[i] = 0;
    __syncthreads();
    int e0 = blockIdx.x * ECHUNK;
    int e1 = e0 + ECHUNK; if (e1 > N_EDGES) e1 = N_EDGES;
    for (int e = e0 + t; e < e1; e += 256) atomicAdd(&cnt[dst[e] >> 9], 1);
    __syncthreads();
    for (int i = t; i < NBUCK; i += 256) base[i] = cnt[i] ? atomicAdd(&bcursor[i], cnt[i]) : 0;
    __syncthreads();
    for (int i = t; i < NBUCK; i += 256) cnt[i] = 0;
    __syncthreads();
    for (int e = e0 + t; e < e1; e += 256) {
        int d = dst[e];
        int b = d >> 9;
        int r = atomicAdd(&cnt[b], 1);
        ebuf[base[b] + r] = make_int2(src[e], d);
    }
}

__global__ __launch_bounds__(256) void k_bcsr(const int2* __restrict__ ebuf, const int* __restrict__ bbase,
                                              int* __restrict__ offs, int* __restrict__ csr) {
    __shared__ int ldeg[BUCKW];
    __shared__ int lscan[BUCKW];
    __shared__ int lcur[BUCKW];
    int t = threadIdx.x;
    int b = blockIdx.x;
    int nbase = b << 9;
    int ebeg = bbase[b], eend = bbase[b + 1];
    ldeg[t] = 0; ldeg[t + 256] = 0;
    __syncthreads();
    for (int e = ebeg + t; e < eend; e += 256) atomicAdd(&ldeg[ebuf[e].y - nbase], 1);
    __syncthreads();
    lscan[t] = ldeg[t]; lscan[t + 256] = ldeg[t + 256];
    __syncthreads();
    for (int off = 1; off < BUCKW; off <<= 1) {
        int i0 = t, i1 = t + 256;
        int v0 = (i0 >= off) ? lscan[i0 - off] : 0;
        int v1 = (i1 >= off) ? lscan[i1 - off] : 0;
        __syncthreads();
        lscan[i0] += v0; lscan[i1] += v1;
        __syncthreads();
    }
    int ex0 = lscan[t] - ldeg[t];
    int ex1 = lscan[t + 256] - ldeg[t + 256];
    lcur[t] = ex0; lcur[t + 256] = ex1;
    int n0 = nbase + t, n1 = nbase + t + 256;
    if (n0 < N_NODES) offs[n0] = ebeg + ex0;
    if (n1 < N_NODES) offs[n1] = ebeg + ex1;
    if (b == 0 && t == 0) offs[N_NODES] = N_EDGES;
    __syncthreads();
    for (int e = ebeg + t; e < eend; e += 256) {
        int2 p = ebuf[e];
        int slot = atomicAdd(&lcur[p.y - nbase], 1);
        csr[ebeg + slot] = p.x;
    }
}

// ---------------- x (fp32) -> bf16 ----------------
__global__ __launch_bounds__(256) void k_x2bf(const float* __restrict__ x, bfu* __restrict__ xb) {
    int i = blockIdx.x * 256 + threadIdx.x;   // quad index; grid covers exactly N*64/4
    int base = i * 4;
    float4 v = *(const float4*)&x[base];
    ushort4 o;
    o.x = f2bf(v.x); o.y = f2bf(v.y); o.z = f2bf(v.z); o.w = f2bf(v.w);
    *(ushort4*)&xb[base] = o;
}

// ---------------- per-layer: aggregation (bf16 gather, fp32 accum) ----------------
__global__ __launch_bounds__(256) void k_agg(const bfu* __restrict__ feat, const int* __restrict__ offs,
                                             const int* __restrict__ csr, const float* __restrict__ eps,
                                             int l, bfu* __restrict__ hin) {
    int w = threadIdx.x >> 6;
    int lane = threadIdx.x & 63;
    int node = blockIdx.x * 4 + w;
    if (node >= N_NODES) return;
    int e0 = offs[node], e1 = offs[node + 1];
    int eL = e1 - 1;
    float acc = 0.f;
    for (int e = e0; e < e1; e += 8) {
        int i1 = (e + 1 < eL) ? e + 1 : eL;
        int i2 = (e + 2 < eL) ? e + 2 : eL;
        int i3 = (e + 3 < eL) ? e + 3 : eL;
        int i4 = (e + 4 < eL) ? e + 4 : eL;
        int i5 = (e + 5 < eL) ? e + 5 : eL;
        int i6 = (e + 6 < eL) ? e + 6 : eL;
        int i7 = (e + 7 < eL) ? e + 7 : eL;
        int s0 = csr[e],  s1 = csr[i1], s2 = csr[i2], s3 = csr[i3];
        int s4 = csr[i4], s5 = csr[i5], s6 = csr[i6], s7 = csr[i7];
        float v0 = bf2f(feat[s0 * DIM + lane]);
        float v1 = (e + 1 <= eL) ? bf2f(feat[s1 * DIM + lane]) : 0.f;
        float v2 = (e + 2 <= eL) ? bf2f(feat[s2 * DIM + lane]) : 0.f;
        float v3 = (e + 3 <= eL) ? bf2f(feat[s3 * DIM + lane]) : 0.f;
        float v4 = (e + 4 <= eL) ? bf2f(feat[s4 * DIM + lane]) : 0.f;
        float v5 = (e + 5 <= eL) ? bf2f(feat[s5 * DIM + lane]) : 0.f;
        float v6 = (e + 6 <= eL) ? bf2f(feat[s6 * DIM + lane]) : 0.f;
        float v7 = (e + 7 <= eL) ? bf2f(feat[s7 * DIM + lane]) : 0.f;
        acc += ((v0 + v1) + (v2 + v3)) + ((v4 + v5) + (v6 + v7));
    }
    float ep = 1.0f + eps[l];
    hin[node * DIM + lane] = f2bf(ep * bf2f(feat[node * DIM + lane]) + acc);
}

// ---------------- per-layer: conv MLP  h = relu(hin@W1+b1)@W2+b2 (bf16 io, fp32 math) ----------------
__global__ __launch_bounds__(256) void k_mlp(const bfu* __restrict__ hin,
                                             const float* __restrict__ w1, const float* __restrict__ b1,
                                             const float* __restrict__ w2, const float* __restrict__ b2,
                                             bfu* __restrict__ hout) {
    __shared__ __align__(16) float sW1[64 * 64];
    __shared__ __align__(16) float sW2[64 * 64];
    __shared__ __align__(16) float sIn[64 * 68];
    __shared__ __align__(16) float sT[64 * 68];
    __shared__ float sB1[64], sB2[64];
    int t = threadIdx.x;
    int row0 = blockIdx.x * 64;
#pragma unroll
    for (int i = 0; i < 16; i++) {
        sW1[i * 256 + t] = w1[i * 256 + t];
        sW2[i * 256 + t] = w2[i * 256 + t];
    }
    if (t < 64) { sB1[t] = b1[t]; sB2[t] = b2[t]; }
#pragma unroll
    for (int i = 0; i < 4; i++) {
        int idx = i * 256 + t;          // quad index 0..1023
        int r = idx >> 4;               // row 0..63
        int c = (idx & 15) * 4;         // col 0..60
        int row = row0 + r;
        float4 v = {0.f, 0.f, 0.f, 0.f};
        if (row < N_NODES) {
            ushort4 u = *(const ushort4*)&hin[row * 64 + c];
            v.x = bf2f(u.x); v.y = bf2f(u.y); v.z = bf2f(u.z); v.w = bf2f(u.w);
        }
        sIn[r * 68 + c + 0] = v.x; sIn[r * 68 + c + 1] = v.y;
        sIn[r * 68 + c + 2] = v.z; sIn[r * 68 + c + 3] = v.w;
    }
    __syncthreads();

    int c0 = (t & 15) * 4;
    int r0 = (t >> 4) * 4;
    float acc[4][4];
#pragma unroll
    for (int i = 0; i < 4; i++)
#pragma unroll
        for (int j = 0; j < 4; j++) acc[i][j] = sB1[c0 + j];
#pragma unroll 4
    for (int k = 0; k < 64; k++) {
        float4 w = *(const float4*)&sW1[k * 64 + c0];
#pragma unroll
        for (int i = 0; i < 4; i++) {
            float a = sIn[(r0 + i) * 68 + k];
            acc[i][0] += a * w.x; acc[i][1] += a * w.y;
            acc[i][2] += a * w.z; acc[i][3] += a * w.w;
        }
    }
#pragma unroll
    for (int i = 0; i < 4; i++)
#pragma unroll
        for (int j = 0; j < 4; j++)
            sT[(r0 + i) * 68 + c0 + j] = fmaxf(acc[i][j], 0.f);
    __syncthreads();

    float acc2[4][4];
#pragma unroll
    for (int i = 0; i < 4; i++)
#pragma unroll
        for (int j = 0; j < 4; j++) acc2[i][j] = sB2[c0 + j];
#pragma unroll 4
    for (int k = 0; k < 64; k++) {
        float4 w = *(const float4*)&sW2[k * 64 + c0];
#pragma unroll
        for (int i = 0; i < 4; i++) {
            float a = sT[(r0 + i) * 68 + k];
            acc2[i][0] += a * w.x; acc2[i][1] += a * w.y;
            acc2[i][2] += a * w.z; acc2[i][3] += a * w.w;
        }
    }
#pragma unroll
    for (int i = 0; i < 4; i++) {
        int row = row0 + r0 + i;
        if (row < N_NODES) {
            ushort4 o;
            o.x = f2bf(acc2[i][0]); o.y = f2bf(acc2[i][1]);
            o.z = f2bf(acc2[i][2]); o.w = f2bf(acc2[i][3]);
            *(ushort4*)&hout[row * 64 + c0] = o;
        }
    }
}

// ---------------- per-layer: per-graph GraphNorm stats ----------------
__global__ __launch_bounds__(256) void k_stats(const bfu* __restrict__ h,
                                               const int* __restrict__ gstart,
                                               const float* __restrict__ inv_safe,
                                               const float* __restrict__ gnw, const float* __restrict__ gns,
                                               const float* __restrict__ pb2,
                                               float* __restrict__ gms, float* __restrict__ gcoef,
                                               float* __restrict__ out, int l) {
    __shared__ float sRS[4][64];
    __shared__ float sRQ[4][64];
    int t = threadIdx.x;
    int g = blockIdx.x;
    int s = gstart[g], e = gstart[g + 1];
    int nn = e - s;
    float inv = inv_safe[g];
    int lane = t & 63, q = t >> 6;
    float sum = 0.f, sumsq = 0.f;
    for (int i = s + q; i < e; i += 4) {
        float v = bf2f(h[i * 64 + lane]);
        sum += v;
        sumsq += v * v;
    }
    sRS[q][lane] = sum;
    sRQ[q][lane] = sumsq;
    __syncthreads();
    if (t < 64) {
        float S = sRS[0][t] + sRS[1][t] + sRS[2][t] + sRS[3][t];
        float Q = sRQ[0][t] + sRQ[1][t] + sRQ[2][t] + sRQ[3][t];
        float m = S * inv;
        float ms = m * gns[t];
        float var = (Q - 2.f * ms * S + (float)nn * ms * ms) * inv;
        gms[g * 64 + t] = ms;
        gcoef[g * 64 + t] = gnw[t] * rsqrtf(var + 1e-8f);
    }
    if (t < TDIM) {
        out[g * (NLAYERS * TDIM) + l * TDIM + t] = (nn > 0) ? pb2[t] : 0.f;
    }
}

// ---------------- per-layer: apply norm+relu, proj MLP, segmented pooling ----------------
__global__ __launch_bounds__(256) void k_apply_proj(const bfu* __restrict__ h,
                                                    const int* __restrict__ gid,
                                                    const float* __restrict__ gms,
                                                    const float* __restrict__ gcoef,
                                                    const float* __restrict__ gnb,
                                                    const float* __restrict__ inv_safe,
                                                    const float* __restrict__ p1, const float* __restrict__ pb1,
                                                    const float* __restrict__ p2,
                                                    bfu* __restrict__ feat, float* __restrict__ out, int l) {
    __shared__ __align__(16) float sP1[64 * 64];
    __shared__ __align__(16) float sP2[64 * 32];
    __shared__ __align__(16) float sFeat[64 * 68];   // first 64*32 floats reused as sZ
    __shared__ __align__(16) float sM[64 * 68];
    __shared__ float sPB1[64];
    __shared__ int sGid[64];
    float* sZ = sFeat;  // alias, stride 32; safe after GEMM1 completes

    int t = threadIdx.x;
    int row0 = blockIdx.x * 64;
#pragma unroll
    for (int i = 0; i < 16; i++) sP1[i * 256 + t] = p1[i * 256 + t];
#pragma unroll
    for (int i = 0; i < 8; i++) sP2[i * 256 + t] = p2[i * 256 + t];
    if (t < 64) {
        sPB1[t] = pb1[t];
        int row = row0 + t;
        sGid[t] = (row < N_NODES) ? gid[row] : -1;
    }

#pragma unroll
    for (int i = 0; i < 4; i++) {
        int idx = i * 256 + t;          // quad index
        int r = idx >> 4;
        int c = (idx & 15) * 4;
        int row = row0 + r;
        float v0 = 0.f, v1 = 0.f, v2 = 0.f, v3 = 0.f;
        if (row < N_NODES) {
            int g = gid[row];
            ushort4 u = *(const ushort4*)&h[row * 64 + c];
            float4 ms = *(const float4*)&gms[g * 64 + c];
            float4 cf = *(const float4*)&gcoef[g * 64 + c];
            float4 gb = *(const float4*)&gnb[c];
            v0 = fmaxf(cf.x * (bf2f(u.x) - ms.x) + gb.x, 0.f);
            v1 = fmaxf(cf.y * (bf2f(u.y) - ms.y) + gb.y, 0.f);
            v2 = fmaxf(cf.z * (bf2f(u.z) - ms.z) + gb.z, 0.f);
            v3 = fmaxf(cf.w * (bf2f(u.w) - ms.w) + gb.w, 0.f);
            ushort4 fo;
            fo.x = f2bf(v0); fo.y = f2bf(v1); fo.z = f2bf(v2); fo.w = f2bf(v3);
            *(ushort4*)&feat[row * 64 + c] = fo;
        }
        sFeat[r * 68 + c + 0] = v0; sFeat[r * 68 + c + 1] = v1;
        sFeat[r * 68 + c + 2] = v2; sFeat[r * 68 + c + 3] = v3;
    }
    __syncthreads();

    int c0 = (t & 15) * 4;
    int r0 = (t >> 4) * 4;
    float acc[4][4];
#pragma unroll
    for (int i = 0; i < 4; i++)
#pragma unroll
        for (int j = 0; j < 4; j++) acc[i][j] = sPB1[c0 + j];
#pragma unroll 4
    for (int k = 0; k < 64; k++) {
        float4 w = *(const float4*)&sP1[k * 64 + c0];
#pragma unroll
        for (int i = 0; i < 4; i++) {
            float a = sFeat[(r0 + i) * 68 + k];
            acc[i][0] += a * w.x; acc[i][1] += a * w.y;
            acc[i][2] += a * w.z; acc[i][3] += a * w.w;
        }
    }
#pragma unroll
    for (int i = 0; i < 4; i++)
#pragma unroll
        for (int j = 0; j < 4; j++)
            sM[(r0 + i) * 68 + c0 + j] = fmaxf(acc[i][j], 0.f);
    __syncthreads();

    int r2 = (t >> 3) * 2;
    int cz = (t & 7) * 4;
    float z0[4] = {0.f, 0.f, 0.f, 0.f};
    float z1[4] = {0.f, 0.f, 0.f, 0.f};
#pragma unroll 4
    for (int k = 0; k < 64; k++) {
        float4 w = *(const float4*)&sP2[k * 32 + cz];
        float x0 = sM[r2 * 68 + k];
        float x1 = sM[(r2 + 1) * 68 + k];
        z0[0] += x0 * w.x; z0[1] += x0 * w.y; z0[2] += x0 * w.z; z0[3] += x0 * w.w;
        z1[0] += x1 * w.x; z1[1] += x1 * w.y; z1[2] += x1 * w.z; z1[3] += x1 * w.w;
    }
#pragma unroll
    for (int j = 0; j < 4; j++) {
        sZ[r2 * 32 + cz + j] = z0[j];
        sZ[(r2 + 1) * 32 + cz + j] = z1[j];
    }
    __syncthreads();

    if (t < 32) {
        int cur = sGid[0];
        float a = 0.f;
        for (int r = 0; r < 64; r++) {
            int g = sGid[r];
            if (g != cur) {
                if (cur >= 0) atomicAdd(&out[cur * (NLAYERS * TDIM) + l * TDIM + t], a * inv_safe[cur]);
                cur = g;
                a = 0.f;
            }
            if (g >= 0) a += sZ[r * 32 + t];
        }
        if (cur >= 0) atomicAdd(&out[cur * (NLAYERS * TDIM) + l * TDIM + t], a * inv_safe[cur]);
    }
}

// ---------------- launcher ----------------

extern "C" void kernel_launch(void* const* d_in, const int* in_sizes, int n_in,
                              void* d_out, int out_size, void* d_ws, size_t ws_size,
                              hipStream_t stream) {
    const float* x        = (const float*)d_in[0];
    const int*   src      = (const int*)d_in[1];
    const int*   dst      = (const int*)d_in[2];
    const int*   gid      = (const int*)d_in[3];
    const float* eps      = (const float*)d_in[4];
    const float* conv_w1  = (const float*)d_in[5];
    const float* conv_b1  = (const float*)d_in[6];
    const float* conv_w2  = (const float*)d_in[7];
    const float* conv_b2  = (const float*)d_in[8];
    const float* gn_w     = (const float*)d_in[9];
    const float* gn_b     = (const float*)d_in[10];
    const float* gn_s     = (const float*)d_in[11];
    const float* proj_w1  = (const float*)d_in[12];
    const float* proj_b1  = (const float*)d_in[13];
    const float* proj_w2  = (const float*)d_in[14];
    const float* proj_b2  = (const float*)d_in[15];
    float* out = (float*)d_out;

    char* ws = (char*)d_ws;
    size_t off = 0;
    auto alloc = [&](size_t bytes) { char* p = ws + off; off += (bytes + 255) & ~(size_t)255; return p; };
    int*   offs     = (int*)alloc(NP * sizeof(int));
    int*   gstart   = (int*)alloc((NGRAPH + 1) * sizeof(int));
    float* inv_safe = (float*)alloc(NGRAPH * sizeof(float));
    int*   bcnt     = (int*)alloc(NBUCK * sizeof(int));
    int*   bbase    = (int*)alloc((NBUCK + 1) * sizeof(int));
    int*   bcursor  = (int*)alloc(NBUCK * sizeof(int));
    int*   csr      = (int*)alloc(N_EDGES * sizeof(int));
    bfu*   featbf   = (bfu*)alloc((size_t)N_NODES * DIM * sizeof(bfu));
    bfu*   hinbf    = (bfu*)alloc((size_t)N_NODES * DIM * sizeof(bfu));
    bfu*   hbufbf   = (bfu*)alloc((size_t)N_NODES * DIM * sizeof(bfu));
    float* gms      = (float*)alloc((size_t)NGRAPH * 64 * sizeof(float));
    float* gcoef    = (float*)alloc((size_t)NGRAPH * 64 * sizeof(float));
    int2*  ebuf     = (int2*)alloc((size_t)N_EDGES * sizeof(int2));   // setup-only

    // setup
    k_graph_start<<<1, 512, 0, stream>>>(gid, gstart, inv_safe);
    hipMemsetAsync(bcnt, 0, NBUCK * sizeof(int), stream);
    k_bhist<<<256, 256, 0, stream>>>(dst, bcnt);
    k_bscan<<<1, 256, 0, stream>>>(bcnt, bbase, bcursor);
    k_bscatter<<<256, 256, 0, stream>>>(src, dst, bcursor, ebuf);
    k_bcsr<<<NBUCK, 256, 0, stream>>>(ebuf, bbase, offs, csr);
    k_x2bf<<<(N_NODES * DIM / 4) / 256, 256, 0, stream>>>(x, featbf);

    int aggbl = (N_NODES + 3) / 4;
    int mlpbl = (N_NODES + 63) / 64;
    for (int l = 0; l < NLAYERS; l++) {
        k_agg<<<aggbl, 256, 0, stream>>>(featbf, offs, csr, eps, l, hinbf);
        k_mlp<<<mlpbl, 256, 0, stream>>>(hinbf, conv_w1 + l * 4096, conv_b1 + l * 64,
                                         conv_w2 + l * 4096, conv_b2 + l * 64, hbufbf);
        k_stats<<<NGRAPH, 256, 0, stream>>>(hbufbf, gstart, inv_safe,
                                            gn_w + l * 64, gn_s + l * 64, proj_b2 + l * 32,
                                            gms, gcoef, out, l);
        k_apply_proj<<<mlpbl, 256, 0, stream>>>(hbufbf, gid, gms, gcoef, gn_b + l * 64,
                                                inv_safe, proj_w1 + l * 4096, proj_b1 + l * 64,
                                                proj_w2 + l * 2048, featbf, out, l);
    }
}

// Round 5
// 583.658 us; speedup vs baseline: 1.4723x; 1.2153x over previous
//
#include <hip/hip_runtime.h>
#include <math.h>

#define N_NODES 100000
#define N_EDGES 1200000
#define DIM 64
#define TDIM 32
#define NLAYERS 3
#define NGRAPH 500
#define NP (N_NODES + 1)

#define BUCKW 512                      // nodes per bucket (dst >> 9)
#define NBUCK ((N_NODES + BUCKW - 1) / BUCKW)   // 196
#define ECHUNK ((N_EDGES + 255) / 256)          // 4688 edges per block (256 blocks)

typedef unsigned short bfu;

__device__ __forceinline__ float bf2f(bfu u) {
    union { unsigned int i; float f; } v; v.i = ((unsigned int)u) << 16; return v.f;
}
__device__ __forceinline__ float bflo(unsigned int d) {
    union { unsigned int i; float f; } v; v.i = d << 16; return v.f;
}
__device__ __forceinline__ float bfhi(unsigned int d) {
    union { unsigned int i; float f; } v; v.i = d & 0xFFFF0000u; return v.f;
}
__device__ __forceinline__ bfu f2bf(float f) {
    union { float f; unsigned int i; } v; v.f = f;
    unsigned int r = v.i + 0x7FFFu + ((v.i >> 16) & 1u);   // RNE
    return (bfu)(r >> 16);
}

// ---------------- setup: graph ranges ----------------

__global__ __launch_bounds__(512) void k_graph_start(const int* __restrict__ gid,
                                                     int* __restrict__ gstart,
                                                     float* __restrict__ inv_safe) {
    int t = threadIdx.x;
    if (t <= NGRAPH) {
        int lo = 0, hi = N_NODES;
        while (lo < hi) {
            int mid = (lo + hi) >> 1;
            if (gid[mid] < t) lo = mid + 1; else hi = mid;
        }
        gstart[t] = lo;
    }
    __syncthreads();
    if (t < NGRAPH) {
        int c = gstart[t + 1] - gstart[t];
        inv_safe[t] = 1.0f / (float)(c > 1 ? c : 1);
    }
}

// ---------------- setup: bucketed CSR build ----------------

__global__ __launch_bounds__(256) void k_bhist(const int* __restrict__ dst, int* __restrict__ bcnt) {
    __shared__ int h[NBUCK];
    int t = threadIdx.x;
    for (int i = t; i < NBUCK; i += 256) h[i] = 0;
    __syncthreads();
    int e0 = blockIdx.x * ECHUNK;
    int e1 = e0 + ECHUNK; if (e1 > N_EDGES) e1 = N_EDGES;
    for (int e = e0 + t; e < e1; e += 256) atomicAdd(&h[dst[e] >> 9], 1);
    __syncthreads();
    for (int i = t; i < NBUCK; i += 256) if (h[i]) atomicAdd(&bcnt[i], h[i]);
}

__global__ __launch_bounds__(256) void k_bscan(const int* __restrict__ bcnt,
                                               int* __restrict__ bbase, int* __restrict__ bcursor) {
    __shared__ int s[256];
    int t = threadIdx.x;
    s[t] = (t < NBUCK) ? bcnt[t] : 0;
    __syncthreads();
    for (int off = 1; off < 256; off <<= 1) {
        int v = (t >= off) ? s[t - off] : 0;
        __syncthreads();
        s[t] += v;
        __syncthreads();
    }
    int ex = t ? s[t - 1] : 0;
    if (t < NBUCK) { bbase[t] = ex; bcursor[t] = ex; }
    if (t == 0) bbase[NBUCK] = N_EDGES;
}

__global__ __launch_bounds__(256) void k_bscatter(const int* __restrict__ src, const int* __restrict__ dst,
                                                  int* __restrict__ bcursor, int2* __restrict__ ebuf) {
    __shared__ int cnt[NBUCK];
    __shared__ int base[NBUCK];
    int t = threadIdx.x;
    for (int i = t; i < NBUCK; i += 256) cnt[i] = 0;
    __syncthreads();
    int e0 = blockIdx.x * ECHUNK;
    int e1 = e0 + ECHUNK; if (e1 > N_EDGES) e1 = N_EDGES;
    for (int e = e0 + t; e < e1; e += 256) atomicAdd(&cnt[dst[e] >> 9], 1);
    __syncthreads();
    for (int i = t; i < NBUCK; i += 256) base[i] = cnt[i] ? atomicAdd(&bcursor[i], cnt[i]) : 0;
    __syncthreads();
    for (int i = t; i < NBUCK; i += 256) cnt[i] = 0;
    __syncthreads();
    for (int e = e0 + t; e < e1; e += 256) {
        int d = dst[e];
        int b = d >> 9;
        int r = atomicAdd(&cnt[b], 1);
        ebuf[base[b] + r] = make_int2(src[e], d);
    }
}

__global__ __launch_bounds__(256) void k_bcsr(const int2* __restrict__ ebuf, const int* __restrict__ bbase,
                                              int* __restrict__ offs, int* __restrict__ csr) {
    __shared__ int ldeg[BUCKW];
    __shared__ int lscan[BUCKW];
    __shared__ int lcur[BUCKW];
    int t = threadIdx.x;
    int b = blockIdx.x;
    int nbase = b << 9;
    int ebeg = bbase[b], eend = bbase[b + 1];
    ldeg[t] = 0; ldeg[t + 256] = 0;
    __syncthreads();
    for (int e = ebeg + t; e < eend; e += 256) atomicAdd(&ldeg[ebuf[e].y - nbase], 1);
    __syncthreads();
    lscan[t] = ldeg[t]; lscan[t + 256] = ldeg[t + 256];
    __syncthreads();
    for (int off = 1; off < BUCKW; off <<= 1) {
        int i0 = t, i1 = t + 256;
        int v0 = (i0 >= off) ? lscan[i0 - off] : 0;
        int v1 = (i1 >= off) ? lscan[i1 - off] : 0;
        __syncthreads();
        lscan[i0] += v0; lscan[i1] += v1;
        __syncthreads();
    }
    int ex0 = lscan[t] - ldeg[t];
    int ex1 = lscan[t + 256] - ldeg[t + 256];
    lcur[t] = ex0; lcur[t + 256] = ex1;
    int n0 = nbase + t, n1 = nbase + t + 256;
    if (n0 < N_NODES) offs[n0] = ebeg + ex0;
    if (n1 < N_NODES) offs[n1] = ebeg + ex1;
    if (b == 0 && t == 0) offs[N_NODES] = N_EDGES;
    __syncthreads();
    for (int e = ebeg + t; e < eend; e += 256) {
        int2 p = ebuf[e];
        int slot = atomicAdd(&lcur[p.y - nbase], 1);
        csr[ebeg + slot] = p.x;
    }
}

// ---------------- x (fp32) -> bf16 ----------------
__global__ __launch_bounds__(256) void k_x2bf(const float* __restrict__ x, bfu* __restrict__ xb) {
    int i = blockIdx.x * 256 + threadIdx.x;   // quad index; grid covers exactly N*64/4
    int base = i * 4;
    float4 v = *(const float4*)&x[base];
    ushort4 o;
    o.x = f2bf(v.x); o.y = f2bf(v.y); o.z = f2bf(v.z); o.w = f2bf(v.w);
    *(ushort4*)&xb[base] = o;
}

// ---------------- per-layer: aggregation ----------------
// One wave per node. lane = eidx*8 + chunk: each lane loads a 16B chunk (8 bf16
// channels) of edge (e+eidx)'s source row -> one dwordx4 instruction gathers 8
// full rows (1 KB/wave-inst) instead of 8 separate 128B row-gathers.
__device__ __forceinline__ void accum8(float* acc, uint4 d) {
    acc[0] += bflo(d.x); acc[1] += bfhi(d.x);
    acc[2] += bflo(d.y); acc[3] += bfhi(d.y);
    acc[4] += bflo(d.z); acc[5] += bfhi(d.z);
    acc[6] += bflo(d.w); acc[7] += bfhi(d.w);
}

__global__ __launch_bounds__(256) void k_agg(const bfu* __restrict__ feat, const int* __restrict__ offs,
                                             const int* __restrict__ csr, const float* __restrict__ eps,
                                             int l, bfu* __restrict__ hin) {
    int w = threadIdx.x >> 6;
    int lane = threadIdx.x & 63;
    int node = blockIdx.x * 4 + w;
    if (node >= N_NODES) return;
    int eidx = lane >> 3;          // which of 8 concurrent edges
    int chunk = lane & 7;          // which 16B chunk of the 128B row
    int coff = chunk * 8;          // channel offset
    int e0 = offs[node], e1 = offs[node + 1];
    int eL = e1 - 1;
    float acc[8] = {0.f, 0.f, 0.f, 0.f, 0.f, 0.f, 0.f, 0.f};

    for (int e = e0; e < e1; e += 16) {
        int ea = e + eidx;
        int ca = (ea < eL) ? ea : eL;
        int sa = csr[ca];
        uint4 da = *(const uint4*)&feat[sa * DIM + coff];
        bool two = (e + 8) < e1;           // wave-uniform
        if (two) {
            int ebi = e + 8 + eidx;
            int cb = (ebi < eL) ? ebi : eL;
            int sb = csr[cb];
            uint4 db = *(const uint4*)&feat[sb * DIM + coff];
            if (ea >= e1) da = make_uint4(0u, 0u, 0u, 0u);
            if (ebi >= e1) db = make_uint4(0u, 0u, 0u, 0u);
            accum8(acc, da);
            accum8(acc, db);
        } else {
            if (ea >= e1) da = make_uint4(0u, 0u, 0u, 0u);
            accum8(acc, da);
        }
    }

    // reduce across the 8 eidx groups (lane stride 8)
#pragma unroll
    for (int j = 0; j < 8; j++) {
        float v = acc[j];
        v += __shfl_xor(v, 8, 64);
        v += __shfl_xor(v, 16, 64);
        v += __shfl_xor(v, 32, 64);
        acc[j] = v;
    }

    // self term + store (8 lanes write the 128B row)
    float ep = 1.0f + eps[l];
    uint4 s = *(const uint4*)&feat[node * DIM + coff];
    float r0 = ep * bflo(s.x) + acc[0], r1 = ep * bfhi(s.x) + acc[1];
    float r2 = ep * bflo(s.y) + acc[2], r3 = ep * bfhi(s.y) + acc[3];
    float r4 = ep * bflo(s.z) + acc[4], r5 = ep * bfhi(s.z) + acc[5];
    float r6 = ep * bflo(s.w) + acc[6], r7 = ep * bfhi(s.w) + acc[7];
    if (eidx == 0) {
        uint4 o;
        o.x = ((unsigned int)f2bf(r1) << 16) | f2bf(r0);
        o.y = ((unsigned int)f2bf(r3) << 16) | f2bf(r2);
        o.z = ((unsigned int)f2bf(r5) << 16) | f2bf(r4);
        o.w = ((unsigned int)f2bf(r7) << 16) | f2bf(r6);
        *(uint4*)&hin[node * DIM + coff] = o;
    }
}

// ---------------- per-layer: conv MLP  h = relu(hin@W1+b1)@W2+b2 (bf16 io, fp32 math) ----------------
__global__ __launch_bounds__(256) void k_mlp(const bfu* __restrict__ hin,
                                             const float* __restrict__ w1, const float* __restrict__ b1,
                                             const float* __restrict__ w2, const float* __restrict__ b2,
                                             bfu* __restrict__ hout) {
    __shared__ __align__(16) float sW1[64 * 64];
    __shared__ __align__(16) float sW2[64 * 64];
    __shared__ __align__(16) float sIn[64 * 68];
    __shared__ __align__(16) float sT[64 * 68];
    __shared__ float sB1[64], sB2[64];
    int t = threadIdx.x;
    int row0 = blockIdx.x * 64;
#pragma unroll
    for (int i = 0; i < 16; i++) {
        sW1[i * 256 + t] = w1[i * 256 + t];
        sW2[i * 256 + t] = w2[i * 256 + t];
    }
    if (t < 64) { sB1[t] = b1[t]; sB2[t] = b2[t]; }
#pragma unroll
    for (int i = 0; i < 4; i++) {
        int idx = i * 256 + t;          // quad index 0..1023
        int r = idx >> 4;               // row 0..63
        int c = (idx & 15) * 4;         // col 0..60
        int row = row0 + r;
        float4 v = {0.f, 0.f, 0.f, 0.f};
        if (row < N_NODES) {
            ushort4 u = *(const ushort4*)&hin[row * 64 + c];
            v.x = bf2f(u.x); v.y = bf2f(u.y); v.z = bf2f(u.z); v.w = bf2f(u.w);
        }
        sIn[r * 68 + c + 0] = v.x; sIn[r * 68 + c + 1] = v.y;
        sIn[r * 68 + c + 2] = v.z; sIn[r * 68 + c + 3] = v.w;
    }
    __syncthreads();

    int c0 = (t & 15) * 4;
    int r0 = (t >> 4) * 4;
    float acc[4][4];
#pragma unroll
    for (int i = 0; i < 4; i++)
#pragma unroll
        for (int j = 0; j < 4; j++) acc[i][j] = sB1[c0 + j];
#pragma unroll 4
    for (int k = 0; k < 64; k++) {
        float4 w = *(const float4*)&sW1[k * 64 + c0];
#pragma unroll
        for (int i = 0; i < 4; i++) {
            float a = sIn[(r0 + i) * 68 + k];
            acc[i][0] += a * w.x; acc[i][1] += a * w.y;
            acc[i][2] += a * w.z; acc[i][3] += a * w.w;
        }
    }
#pragma unroll
    for (int i = 0; i < 4; i++)
#pragma unroll
        for (int j = 0; j < 4; j++)
            sT[(r0 + i) * 68 + c0 + j] = fmaxf(acc[i][j], 0.f);
    __syncthreads();

    float acc2[4][4];
#pragma unroll
    for (int i = 0; i < 4; i++)
#pragma unroll
        for (int j = 0; j < 4; j++) acc2[i][j] = sB2[c0 + j];
#pragma unroll 4
    for (int k = 0; k < 64; k++) {
        float4 w = *(const float4*)&sW2[k * 64 + c0];
#pragma unroll
        for (int i = 0; i < 4; i++) {
            float a = sT[(r0 + i) * 68 + k];
            acc2[i][0] += a * w.x; acc2[i][1] += a * w.y;
            acc2[i][2] += a * w.z; acc2[i][3] += a * w.w;
        }
    }
#pragma unroll
    for (int i = 0; i < 4; i++) {
        int row = row0 + r0 + i;
        if (row < N_NODES) {
            ushort4 o;
            o.x = f2bf(acc2[i][0]); o.y = f2bf(acc2[i][1]);
            o.z = f2bf(acc2[i][2]); o.w = f2bf(acc2[i][3]);
            *(ushort4*)&hout[row * 64 + c0] = o;
        }
    }
}

// ---------------- per-layer: per-graph GraphNorm stats ----------------
__global__ __launch_bounds__(256) void k_stats(const bfu* __restrict__ h,
                                               const int* __restrict__ gstart,
                                               const float* __restrict__ inv_safe,
                                               const float* __restrict__ gnw, const float* __restrict__ gns,
                                               const float* __restrict__ pb2,
                                               float* __restrict__ gms, float* __restrict__ gcoef,
                                               float* __restrict__ out, int l) {
    __shared__ float sRS[4][64];
    __shared__ float sRQ[4][64];
    int t = threadIdx.x;
    int g = blockIdx.x;
    int s = gstart[g], e = gstart[g + 1];
    int nn = e - s;
    float inv = inv_safe[g];
    int lane = t & 63, q = t >> 6;
    float sum = 0.f, sumsq = 0.f;
    for (int i = s + q; i < e; i += 4) {
        float v = bf2f(h[i * 64 + lane]);
        sum += v;
        sumsq += v * v;
    }
    sRS[q][lane] = sum;
    sRQ[q][lane] = sumsq;
    __syncthreads();
    if (t < 64) {
        float S = sRS[0][t] + sRS[1][t] + sRS[2][t] + sRS[3][t];
        float Q = sRQ[0][t] + sRQ[1][t] + sRQ[2][t] + sRQ[3][t];
        float m = S * inv;
        float ms = m * gns[t];
        float var = (Q - 2.f * ms * S + (float)nn * ms * ms) * inv;
        gms[g * 64 + t] = ms;
        gcoef[g * 64 + t] = gnw[t] * rsqrtf(var + 1e-8f);
    }
    if (t < TDIM) {
        out[g * (NLAYERS * TDIM) + l * TDIM + t] = (nn > 0) ? pb2[t] : 0.f;
    }
}

// ---------------- per-layer: apply norm+relu, proj MLP, segmented pooling ----------------
__global__ __launch_bounds__(256) void k_apply_proj(const bfu* __restrict__ h,
                                                    const int* __restrict__ gid,
                                                    const float* __restrict__ gms,
                                                    const float* __restrict__ gcoef,
                                                    const float* __restrict__ gnb,
                                                    const float* __restrict__ inv_safe,
                                                    const float* __restrict__ p1, const float* __restrict__ pb1,
                                                    const float* __restrict__ p2,
                                                    bfu* __restrict__ feat, float* __restrict__ out, int l) {
    __shared__ __align__(16) float sP1[64 * 64];
    __shared__ __align__(16) float sP2[64 * 32];
    __shared__ __align__(16) float sFeat[64 * 68];   // first 64*32 floats reused as sZ
    __shared__ __align__(16) float sM[64 * 68];
    __shared__ float sPB1[64];
    __shared__ int sGid[64];
    float* sZ = sFeat;  // alias, stride 32; safe after GEMM1 completes

    int t = threadIdx.x;
    int row0 = blockIdx.x * 64;
#pragma unroll
    for (int i = 0; i < 16; i++) sP1[i * 256 + t] = p1[i * 256 + t];
#pragma unroll
    for (int i = 0; i < 8; i++) sP2[i * 256 + t] = p2[i * 256 + t];
    if (t < 64) {
        sPB1[t] = pb1[t];
        int row = row0 + t;
        sGid[t] = (row < N_NODES) ? gid[row] : -1;
    }

#pragma unroll
    for (int i = 0; i < 4; i++) {
        int idx = i * 256 + t;          // quad index
        int r = idx >> 4;
        int c = (idx & 15) * 4;
        int row = row0 + r;
        float v0 = 0.f, v1 = 0.f, v2 = 0.f, v3 = 0.f;
        if (row < N_NODES) {
            int g = gid[row];
            ushort4 u = *(const ushort4*)&h[row * 64 + c];
            float4 ms = *(const float4*)&gms[g * 64 + c];
            float4 cf = *(const float4*)&gcoef[g * 64 + c];
            float4 gb = *(const float4*)&gnb[c];
            v0 = fmaxf(cf.x * (bf2f(u.x) - ms.x) + gb.x, 0.f);
            v1 = fmaxf(cf.y * (bf2f(u.y) - ms.y) + gb.y, 0.f);
            v2 = fmaxf(cf.z * (bf2f(u.z) - ms.z) + gb.z, 0.f);
            v3 = fmaxf(cf.w * (bf2f(u.w) - ms.w) + gb.w, 0.f);
            ushort4 fo;
            fo.x = f2bf(v0); fo.y = f2bf(v1); fo.z = f2bf(v2); fo.w = f2bf(v3);
            *(ushort4*)&feat[row * 64 + c] = fo;
        }
        sFeat[r * 68 + c + 0] = v0; sFeat[r * 68 + c + 1] = v1;
        sFeat[r * 68 + c + 2] = v2; sFeat[r * 68 + c + 3] = v3;
    }
    __syncthreads();

    int c0 = (t & 15) * 4;
    int r0 = (t >> 4) * 4;
    float acc[4][4];
#pragma unroll
    for (int i = 0; i < 4; i++)
#pragma unroll
        for (int j = 0; j < 4; j++) acc[i][j] = sPB1[c0 + j];
#pragma unroll 4
    for (int k = 0; k < 64; k++) {
        float4 w = *(const float4*)&sP1[k * 64 + c0];
#pragma unroll
        for (int i = 0; i < 4; i++) {
            float a = sFeat[(r0 + i) * 68 + k];
            acc[i][0] += a * w.x; acc[i][1] += a * w.y;
            acc[i][2] += a * w.z; acc[i][3] += a * w.w;
        }
    }
#pragma unroll
    for (int i = 0; i < 4; i++)
#pragma unroll
        for (int j = 0; j < 4; j++)
            sM[(r0 + i) * 68 + c0 + j] = fmaxf(acc[i][j], 0.f);
    __syncthreads();

    int r2 = (t >> 3) * 2;
    int cz = (t & 7) * 4;
    float z0[4] = {0.f, 0.f, 0.f, 0.f};
    float z1[4] = {0.f, 0.f, 0.f, 0.f};
#pragma unroll 4
    for (int k = 0; k < 64; k++) {
        float4 w = *(const float4*)&sP2[k * 32 + cz];
        float x0 = sM[r2 * 68 + k];
        float x1 = sM[(r2 + 1) * 68 + k];
        z0[0] += x0 * w.x; z0[1] += x0 * w.y; z0[2] += x0 * w.z; z0[3] += x0 * w.w;
        z1[0] += x1 * w.x; z1[1] += x1 * w.y; z1[2] += x1 * w.z; z1[3] += x1 * w.w;
    }
#pragma unroll
    for (int j = 0; j < 4; j++) {
        sZ[r2 * 32 + cz + j] = z0[j];
        sZ[(r2 + 1) * 32 + cz + j] = z1[j];
    }
    __syncthreads();

    if (t < 32) {
        int cur = sGid[0];
        float a = 0.f;
        for (int r = 0; r < 64; r++) {
            int g = sGid[r];
            if (g != cur) {
                if (cur >= 0) atomicAdd(&out[cur * (NLAYERS * TDIM) + l * TDIM + t], a * inv_safe[cur]);
                cur = g;
                a = 0.f;
            }
            if (g >= 0) a += sZ[r * 32 + t];
        }
        if (cur >= 0) atomicAdd(&out[cur * (NLAYERS * TDIM) + l * TDIM + t], a * inv_safe[cur]);
    }
}

// ---------------- launcher ----------------

extern "C" void kernel_launch(void* const* d_in, const int* in_sizes, int n_in,
                              void* d_out, int out_size, void* d_ws, size_t ws_size,
                              hipStream_t stream) {
    const float* x        = (const float*)d_in[0];
    const int*   src      = (const int*)d_in[1];
    const int*   dst      = (const int*)d_in[2];
    const int*   gid      = (const int*)d_in[3];
    const float* eps      = (const float*)d_in[4];
    const float* conv_w1  = (const float*)d_in[5];
    const float* conv_b1  = (const float*)d_in[6];
    const float* conv_w2  = (const float*)d_in[7];
    const float* conv_b2  = (const float*)d_in[8];
    const float* gn_w     = (const float*)d_in[9];
    const float* gn_b     = (const float*)d_in[10];
    const float* gn_s     = (const float*)d_in[11];
    const float* proj_w1  = (const float*)d_in[12];
    const float* proj_b1  = (const float*)d_in[13];
    const float* proj_w2  = (const float*)d_in[14];
    const float* proj_b2  = (const float*)d_in[15];
    float* out = (float*)d_out;

    char* ws = (char*)d_ws;
    size_t off = 0;
    auto alloc = [&](size_t bytes) { char* p = ws + off; off += (bytes + 255) & ~(size_t)255; return p; };
    int*   offs     = (int*)alloc(NP * sizeof(int));
    int*   gstart   = (int*)alloc((NGRAPH + 1) * sizeof(int));
    float* inv_safe = (float*)alloc(NGRAPH * sizeof(float));
    int*   bcnt     = (int*)alloc(NBUCK * sizeof(int));
    int*   bbase    = (int*)alloc((NBUCK + 1) * sizeof(int));
    int*   bcursor  = (int*)alloc(NBUCK * sizeof(int));
    int*   csr      = (int*)alloc(N_EDGES * sizeof(int));
    bfu*   featbf   = (bfu*)alloc((size_t)N_NODES * DIM * sizeof(bfu));
    bfu*   hinbf    = (bfu*)alloc((size_t)N_NODES * DIM * sizeof(bfu));
    bfu*   hbufbf   = (bfu*)alloc((size_t)N_NODES * DIM * sizeof(bfu));
    float* gms      = (float*)alloc((size_t)NGRAPH * 64 * sizeof(float));
    float* gcoef    = (float*)alloc((size_t)NGRAPH * 64 * sizeof(float));
    int2*  ebuf     = (int2*)alloc((size_t)N_EDGES * sizeof(int2));   // setup-only

    // setup
    k_graph_start<<<1, 512, 0, stream>>>(gid, gstart, inv_safe);
    hipMemsetAsync(bcnt, 0, NBUCK * sizeof(int), stream);
    k_bhist<<<256, 256, 0, stream>>>(dst, bcnt);
    k_bscan<<<1, 256, 0, stream>>>(bcnt, bbase, bcursor);
    k_bscatter<<<256, 256, 0, stream>>>(src, dst, bcursor, ebuf);
    k_bcsr<<<NBUCK, 256, 0, stream>>>(ebuf, bbase, offs, csr);
    k_x2bf<<<(N_NODES * DIM / 4) / 256, 256, 0, stream>>>(x, featbf);

    int aggbl = (N_NODES + 3) / 4;
    int mlpbl = (N_NODES + 63) / 64;
    for (int l = 0; l < NLAYERS; l++) {
        k_agg<<<aggbl, 256, 0, stream>>>(featbf, offs, csr, eps, l, hinbf);
        k_mlp<<<mlpbl, 256, 0, stream>>>(hinbf, conv_w1 + l * 4096, conv_b1 + l * 64,
                                         conv_w2 + l * 4096, conv_b2 + l * 64, hbufbf);
        k_stats<<<NGRAPH, 256, 0, stream>>>(hbufbf, gstart, inv_safe,
                                            gn_w + l * 64, gn_s + l * 64, proj_b2 + l * 32,
                                            gms, gcoef, out, l);
        k_apply_proj<<<mlpbl, 256, 0, stream>>>(hbufbf, gid, gms, gcoef, gn_b + l * 64,
                                                inv_safe, proj_w1 + l * 4096, proj_b1 + l * 64,
                                                proj_w2 + l * 2048, featbf, out, l);
    }
}

// Round 6
// 455.310 us; speedup vs baseline: 1.8873x; 1.2819x over previous
//
#include <hip/hip_runtime.h>
#include <math.h>

#define N_NODES 100000
#define N_EDGES 1200000
#define DIM 64
#define TDIM 32
#define NLAYERS 3
#define NGRAPH 500
#define NP (N_NODES + 1)

#define BUCKW 512                      // nodes per bucket (dst >> 9)
#define NBUCK ((N_NODES + BUCKW - 1) / BUCKW)   // 196
#define ECHUNK ((N_EDGES + 255) / 256)          // 4688 edges per block (256 blocks)

typedef unsigned short bfu;
typedef __attribute__((ext_vector_type(8))) short short8;
typedef __attribute__((ext_vector_type(4))) float v4f;

__device__ __forceinline__ float bf2f(bfu u) {
    union { unsigned int i; float f; } v; v.i = ((unsigned int)u) << 16; return v.f;
}
__device__ __forceinline__ float bflo(unsigned int d) {
    union { unsigned int i; float f; } v; v.i = d << 16; return v.f;
}
__device__ __forceinline__ float bfhi(unsigned int d) {
    union { unsigned int i; float f; } v; v.i = d & 0xFFFF0000u; return v.f;
}
__device__ __forceinline__ bfu f2bf(float f) {
    union { float f; unsigned int i; } v; v.f = f;
    unsigned int r = v.i + 0x7FFFu + ((v.i >> 16) & 1u);   // RNE
    return (bfu)(r >> 16);
}

// ---------------- setup: graph ranges ----------------

__global__ __launch_bounds__(512) void k_graph_start(const int* __restrict__ gid,
                                                     int* __restrict__ gstart,
                                                     float* __restrict__ inv_safe) {
    int t = threadIdx.x;
    if (t <= NGRAPH) {
        int lo = 0, hi = N_NODES;
        while (lo < hi) {
            int mid = (lo + hi) >> 1;
            if (gid[mid] < t) lo = mid + 1; else hi = mid;
        }
        gstart[t] = lo;
    }
    __syncthreads();
    if (t < NGRAPH) {
        int c = gstart[t + 1] - gstart[t];
        inv_safe[t] = 1.0f / (float)(c > 1 ? c : 1);
    }
}

// ---------------- setup: weight prep (transpose + bf16) ----------------
// wT[l][n*64+k] = w[l][k*64+n]; enables contiguous 16B B-fragment loads.
__global__ __launch_bounds__(256) void k_wprep(const float* __restrict__ w1, const float* __restrict__ w2,
                                               const float* __restrict__ q1, const float* __restrict__ q2,
                                               bfu* __restrict__ w1t, bfu* __restrict__ w2t,
                                               bfu* __restrict__ q1t, bfu* __restrict__ q2t) {
    int i = blockIdx.x * 256 + threadIdx.x;
    if (i < NLAYERS * 4096) {
        int l = i >> 12, k = (i >> 6) & 63, n = i & 63;
        int o = (l << 12) | (n << 6) | k;
        w1t[o] = f2bf(w1[i]);
        w2t[o] = f2bf(w2[i]);
        q1t[o] = f2bf(q1[i]);
    }
    if (i < NLAYERS * 2048) {
        int l = i >> 11, rem = i & 2047, k = rem >> 5, n = rem & 31;
        q2t[l * 2048 + n * 64 + k] = f2bf(q2[i]);
    }
}

// ---------------- setup: bucketed CSR build ----------------

__global__ __launch_bounds__(256) void k_bhist(const int* __restrict__ dst, int* __restrict__ bcnt) {
    __shared__ int h[NBUCK];
    int t = threadIdx.x;
    for (int i = t; i < NBUCK; i += 256) h[i] = 0;
    __syncthreads();
    int e0 = blockIdx.x * ECHUNK;
    int e1 = e0 + ECHUNK; if (e1 > N_EDGES) e1 = N_EDGES;
    for (int e = e0 + t; e < e1; e += 256) atomicAdd(&h[dst[e] >> 9], 1);
    __syncthreads();
    for (int i = t; i < NBUCK; i += 256) if (h[i]) atomicAdd(&bcnt[i], h[i]);
}

__global__ __launch_bounds__(256) void k_bscan(const int* __restrict__ bcnt,
                                               int* __restrict__ bbase, int* __restrict__ bcursor) {
    __shared__ int s[256];
    int t = threadIdx.x;
    s[t] = (t < NBUCK) ? bcnt[t] : 0;
    __syncthreads();
    for (int off = 1; off < 256; off <<= 1) {
        int v = (t >= off) ? s[t - off] : 0;
        __syncthreads();
        s[t] += v;
        __syncthreads();
    }
    int ex = t ? s[t - 1] : 0;
    if (t < NBUCK) { bbase[t] = ex; bcursor[t] = ex; }
    if (t == 0) bbase[NBUCK] = N_EDGES;
}

__global__ __launch_bounds__(256) void k_bscatter(const int* __restrict__ src, const int* __restrict__ dst,
                                                  int* __restrict__ bcursor, int2* __restrict__ ebuf) {
    __shared__ int cnt[NBUCK];
    __shared__ int base[NBUCK];
    int t = threadIdx.x;
    for (int i = t; i < NBUCK; i += 256) cnt[i] = 0;
    __syncthreads();
    int e0 = blockIdx.x * ECHUNK;
    int e1 = e0 + ECHUNK; if (e1 > N_EDGES) e1 = N_EDGES;
    for (int e = e0 + t; e < e1; e += 256) atomicAdd(&cnt[dst[e] >> 9], 1);
    __syncthreads();
    for (int i = t; i < NBUCK; i += 256) base[i] = cnt[i] ? atomicAdd(&bcursor[i], cnt[i]) : 0;
    __syncthreads();
    for (int i = t; i < NBUCK; i += 256) cnt[i] = 0;
    __syncthreads();
    for (int e = e0 + t; e < e1; e += 256) {
        int d = dst[e];
        int b = d >> 9;
        int r = atomicAdd(&cnt[b], 1);
        ebuf[base[b] + r] = make_int2(src[e], d);
    }
}

__global__ __launch_bounds__(256) void k_bcsr(const int2* __restrict__ ebuf, const int* __restrict__ bbase,
                                              int* __restrict__ offs, int* __restrict__ csr) {
    __shared__ int ldeg[BUCKW];
    __shared__ int lscan[BUCKW];
    __shared__ int lcur[BUCKW];
    int t = threadIdx.x;
    int b = blockIdx.x;
    int nbase = b << 9;
    int ebeg = bbase[b], eend = bbase[b + 1];
    ldeg[t] = 0; ldeg[t + 256] = 0;
    __syncthreads();
    for (int e = ebeg + t; e < eend; e += 256) atomicAdd(&ldeg[ebuf[e].y - nbase], 1);
    __syncthreads();
    lscan[t] = ldeg[t]; lscan[t + 256] = ldeg[t + 256];
    __syncthreads();
    for (int off = 1; off < BUCKW; off <<= 1) {
        int i0 = t, i1 = t + 256;
        int v0 = (i0 >= off) ? lscan[i0 - off] : 0;
        int v1 = (i1 >= off) ? lscan[i1 - off] : 0;
        __syncthreads();
        lscan[i0] += v0; lscan[i1] += v1;
        __syncthreads();
    }
    int ex0 = lscan[t] - ldeg[t];
    int ex1 = lscan[t + 256] - ldeg[t + 256];
    lcur[t] = ex0; lcur[t + 256] = ex1;
    int n0 = nbase + t, n1 = nbase + t + 256;
    if (n0 < N_NODES) offs[n0] = ebeg + ex0;
    if (n1 < N_NODES) offs[n1] = ebeg + ex1;
    if (b == 0 && t == 0) offs[N_NODES] = N_EDGES;
    __syncthreads();
    for (int e = ebeg + t; e < eend; e += 256) {
        int2 p = ebuf[e];
        int slot = atomicAdd(&lcur[p.y - nbase], 1);
        csr[ebeg + slot] = p.x;
    }
}

// ---------------- x (fp32) -> bf16 ----------------
__global__ __launch_bounds__(256) void k_x2bf(const float* __restrict__ x, bfu* __restrict__ xb) {
    int i = blockIdx.x * 256 + threadIdx.x;
    int base = i * 4;
    float4 v = *(const float4*)&x[base];
    ushort4 o;
    o.x = f2bf(v.x); o.y = f2bf(v.y); o.z = f2bf(v.z); o.w = f2bf(v.w);
    *(ushort4*)&xb[base] = o;
}

// ---------------- per-layer: aggregation ----------------
__device__ __forceinline__ void accum8(float* acc, uint4 d) {
    acc[0] += bflo(d.x); acc[1] += bfhi(d.x);
    acc[2] += bflo(d.y); acc[3] += bfhi(d.y);
    acc[4] += bflo(d.z); acc[5] += bfhi(d.z);
    acc[6] += bflo(d.w); acc[7] += bfhi(d.w);
}

__global__ __launch_bounds__(256) void k_agg(const bfu* __restrict__ feat, const int* __restrict__ offs,
                                             const int* __restrict__ csr, const float* __restrict__ eps,
                                             int l, bfu* __restrict__ hin) {
    int w = threadIdx.x >> 6;
    int lane = threadIdx.x & 63;
    int node = blockIdx.x * 4 + w;
    if (node >= N_NODES) return;
    int eidx = lane >> 3;
    int chunk = lane & 7;
    int coff = chunk * 8;
    int e0 = offs[node], e1 = offs[node + 1];
    int eL = e1 - 1;
    float acc[8] = {0.f, 0.f, 0.f, 0.f, 0.f, 0.f, 0.f, 0.f};

    for (int e = e0; e < e1; e += 16) {
        int ea = e + eidx;
        int ca = (ea < eL) ? ea : eL;
        int sa = csr[ca];
        uint4 da = *(const uint4*)&feat[sa * DIM + coff];
        bool two = (e + 8) < e1;
        if (two) {
            int ebi = e + 8 + eidx;
            int cb = (ebi < eL) ? ebi : eL;
            int sb = csr[cb];
            uint4 db = *(const uint4*)&feat[sb * DIM + coff];
            if (ea >= e1) da = make_uint4(0u, 0u, 0u, 0u);
            if (ebi >= e1) db = make_uint4(0u, 0u, 0u, 0u);
            accum8(acc, da);
            accum8(acc, db);
        } else {
            if (ea >= e1) da = make_uint4(0u, 0u, 0u, 0u);
            accum8(acc, da);
        }
    }

#pragma unroll
    for (int j = 0; j < 8; j++) {
        float v = acc[j];
        v += __shfl_xor(v, 8, 64);
        v += __shfl_xor(v, 16, 64);
        v += __shfl_xor(v, 32, 64);
        acc[j] = v;
    }

    float ep = 1.0f + eps[l];
    uint4 s = *(const uint4*)&feat[node * DIM + coff];
    float r0 = ep * bflo(s.x) + acc[0], r1 = ep * bfhi(s.x) + acc[1];
    float r2 = ep * bflo(s.y) + acc[2], r3 = ep * bfhi(s.y) + acc[3];
    float r4 = ep * bflo(s.z) + acc[4], r5 = ep * bfhi(s.z) + acc[5];
    float r6 = ep * bflo(s.w) + acc[6], r7 = ep * bfhi(s.w) + acc[7];
    if (eidx == 0) {
        uint4 o;
        o.x = ((unsigned int)f2bf(r1) << 16) | f2bf(r0);
        o.y = ((unsigned int)f2bf(r3) << 16) | f2bf(r2);
        o.z = ((unsigned int)f2bf(r5) << 16) | f2bf(r4);
        o.w = ((unsigned int)f2bf(r7) << 16) | f2bf(r6);
        *(uint4*)&hin[node * DIM + coff] = o;
    }
}

// ---------------- per-layer: conv MLP via MFMA ----------------
// 4 waves/block, 16 rows/wave. A-frags from global (A[m=lane&15][k=quad*8+j]),
// B-frags from pre-transposed bf16 weights (B[k][n=lane&15]).
// C layout: col=lane&15, row=quad*4+reg. LDS roundtrip converts C->A layout.
__global__ __launch_bounds__(256) void k_mlp(const bfu* __restrict__ hin,
                                             const bfu* __restrict__ w1t, const float* __restrict__ b1,
                                             const bfu* __restrict__ w2t, const float* __restrict__ b2,
                                             bfu* __restrict__ hout) {
    __shared__ bfu ldsT[4][16 * 80];
    int t = threadIdx.x;
    int w = t >> 6, lane = t & 63, m = lane & 15, q = lane >> 4;
    int row0 = blockIdx.x * 64;
    int row = row0 + w * 16 + m;
    bool valid = row < N_NODES;

    short8 a0 = {0, 0, 0, 0, 0, 0, 0, 0}, a1 = a0;
    if (valid) {
        a0 = *(const short8*)&hin[row * 64 + q * 8];
        a1 = *(const short8*)&hin[row * 64 + 32 + q * 8];
    }
    short8 bf1[4][2], bf2[4][2];
#pragma unroll
    for (int ct = 0; ct < 4; ct++)
#pragma unroll
        for (int kk = 0; kk < 2; kk++) {
            bf1[ct][kk] = *(const short8*)&w1t[(ct * 16 + m) * 64 + kk * 32 + q * 8];
            bf2[ct][kk] = *(const short8*)&w2t[(ct * 16 + m) * 64 + kk * 32 + q * 8];
        }

    bfu* tl = ldsT[w];
#pragma unroll
    for (int ct = 0; ct < 4; ct++) {
        float bv = b1[ct * 16 + m];
        v4f acc = {bv, bv, bv, bv};
        acc = __builtin_amdgcn_mfma_f32_16x16x32_bf16(a0, bf1[ct][0], acc, 0, 0, 0);
        acc = __builtin_amdgcn_mfma_f32_16x16x32_bf16(a1, bf1[ct][1], acc, 0, 0, 0);
#pragma unroll
        for (int r = 0; r < 4; r++)
            tl[(q * 4 + r) * 80 + ct * 16 + m] = f2bf(fmaxf(acc[r], 0.f));
    }
    short8 a20 = *(short8*)&tl[m * 80 + q * 8];
    short8 a21 = *(short8*)&tl[m * 80 + 32 + q * 8];
#pragma unroll
    for (int ct = 0; ct < 4; ct++) {
        float bv = b2[ct * 16 + m];
        v4f acc = {bv, bv, bv, bv};
        acc = __builtin_amdgcn_mfma_f32_16x16x32_bf16(a20, bf2[ct][0], acc, 0, 0, 0);
        acc = __builtin_amdgcn_mfma_f32_16x16x32_bf16(a21, bf2[ct][1], acc, 0, 0, 0);
#pragma unroll
        for (int r = 0; r < 4; r++)
            tl[(q * 4 + r) * 80 + ct * 16 + m] = f2bf(acc[r]);
    }
#pragma unroll
    for (int i = 0; i < 2; i++) {
        int idx = i * 64 + lane;
        int r = idx >> 3, ch = (idx & 7) * 8;
        int grow = row0 + w * 16 + r;
        uint4 v = *(uint4*)&tl[r * 80 + ch];
        if (grow < N_NODES) *(uint4*)&hout[grow * 64 + ch] = v;
    }
}

// ---------------- per-layer: per-graph GraphNorm stats ----------------
__global__ __launch_bounds__(256) void k_stats(const bfu* __restrict__ h,
                                               const int* __restrict__ gstart,
                                               const float* __restrict__ inv_safe,
                                               const float* __restrict__ gnw, const float* __restrict__ gns,
                                               const float* __restrict__ pb2,
                                               float* __restrict__ gms, float* __restrict__ gcoef,
                                               float* __restrict__ out, int l) {
    __shared__ float sRS[4][64];
    __shared__ float sRQ[4][64];
    int t = threadIdx.x;
    int g = blockIdx.x;
    int s = gstart[g], e = gstart[g + 1];
    int nn = e - s;
    float inv = inv_safe[g];
    int lane = t & 63, q = t >> 6;
    float sum = 0.f, sumsq = 0.f;
    for (int i = s + q; i < e; i += 4) {
        float v = bf2f(h[i * 64 + lane]);
        sum += v;
        sumsq += v * v;
    }
    sRS[q][lane] = sum;
    sRQ[q][lane] = sumsq;
    __syncthreads();
    if (t < 64) {
        float S = sRS[0][t] + sRS[1][t] + sRS[2][t] + sRS[3][t];
        float Q = sRQ[0][t] + sRQ[1][t] + sRQ[2][t] + sRQ[3][t];
        float m = S * inv;
        float ms = m * gns[t];
        float var = (Q - 2.f * ms * S + (float)nn * ms * ms) * inv;
        gms[g * 64 + t] = ms;
        gcoef[g * 64 + t] = gnw[t] * rsqrtf(var + 1e-8f);
    }
    if (t < TDIM) {
        out[g * (NLAYERS * TDIM) + l * TDIM + t] = (nn > 0) ? pb2[t] : 0.f;
    }
}

// ---------------- per-layer: norm+relu + proj MLP (MFMA) + segmented pooling ----------------
__global__ __launch_bounds__(256) void k_apply_proj(const bfu* __restrict__ h,
                                                    const int* __restrict__ gid,
                                                    const float* __restrict__ gms,
                                                    const float* __restrict__ gcoef,
                                                    const float* __restrict__ gnb,
                                                    const float* __restrict__ inv_safe,
                                                    const bfu* __restrict__ p1t, const float* __restrict__ pb1,
                                                    const bfu* __restrict__ p2t,
                                                    bfu* __restrict__ feat, float* __restrict__ out, int l) {
    __shared__ bfu ldsT[4][16 * 80];
    __shared__ float sZ[64 * 33];
    __shared__ int sGid[64];
    int t = threadIdx.x;
    int w = t >> 6, lane = t & 63, m = lane & 15, q = lane >> 4;
    int row0 = blockIdx.x * 64;
    int row = row0 + w * 16 + m;
    bool valid = row < N_NODES;
    if (t < 64) sGid[t] = (row0 + t < N_NODES) ? gid[row0 + t] : -1;

    union Pack { short8 v; bfu u[8]; uint4 qv; };
    Pack a0, a1;
    a0.qv = make_uint4(0u, 0u, 0u, 0u);
    a1.qv = make_uint4(0u, 0u, 0u, 0u);
    if (valid) {
        int g = gid[row];
#pragma unroll
        for (int kk = 0; kk < 2; kk++) {
            int ch = kk * 32 + q * 8;
            uint4 hv = *(const uint4*)&h[row * 64 + ch];
            float4 msa = *(const float4*)&gms[g * 64 + ch];
            float4 msb = *(const float4*)&gms[g * 64 + ch + 4];
            float4 cfa = *(const float4*)&gcoef[g * 64 + ch];
            float4 cfb = *(const float4*)&gcoef[g * 64 + ch + 4];
            float4 gba = *(const float4*)&gnb[ch];
            float4 gbb = *(const float4*)&gnb[ch + 4];
            Pack& a = kk ? a1 : a0;
            a.u[0] = f2bf(fmaxf(cfa.x * (bflo(hv.x) - msa.x) + gba.x, 0.f));
            a.u[1] = f2bf(fmaxf(cfa.y * (bfhi(hv.x) - msa.y) + gba.y, 0.f));
            a.u[2] = f2bf(fmaxf(cfa.z * (bflo(hv.y) - msa.z) + gba.z, 0.f));
            a.u[3] = f2bf(fmaxf(cfa.w * (bfhi(hv.y) - msa.w) + gba.w, 0.f));
            a.u[4] = f2bf(fmaxf(cfb.x * (bflo(hv.z) - msb.x) + gbb.x, 0.f));
            a.u[5] = f2bf(fmaxf(cfb.y * (bfhi(hv.z) - msb.y) + gbb.y, 0.f));
            a.u[6] = f2bf(fmaxf(cfb.z * (bflo(hv.w) - msb.z) + gbb.z, 0.f));
            a.u[7] = f2bf(fmaxf(cfb.w * (bfhi(hv.w) - msb.w) + gbb.w, 0.f));
            *(uint4*)&feat[row * 64 + ch] = a.qv;
        }
    }

    short8 bf1[4][2], bf2[2][2];
#pragma unroll
    for (int ct = 0; ct < 4; ct++)
#pragma unroll
        for (int kk = 0; kk < 2; kk++)
            bf1[ct][kk] = *(const short8*)&p1t[(ct * 16 + m) * 64 + kk * 32 + q * 8];
#pragma unroll
    for (int ct = 0; ct < 2; ct++)
#pragma unroll
        for (int kk = 0; kk < 2; kk++)
            bf2[ct][kk] = *(const short8*)&p2t[(ct * 16 + m) * 64 + kk * 32 + q * 8];

    bfu* tl = ldsT[w];
#pragma unroll
    for (int ct = 0; ct < 4; ct++) {
        float bv = pb1[ct * 16 + m];
        v4f acc = {bv, bv, bv, bv};
        acc = __builtin_amdgcn_mfma_f32_16x16x32_bf16(a0.v, bf1[ct][0], acc, 0, 0, 0);
        acc = __builtin_amdgcn_mfma_f32_16x16x32_bf16(a1.v, bf1[ct][1], acc, 0, 0, 0);
#pragma unroll
        for (int r = 0; r < 4; r++)
            tl[(q * 4 + r) * 80 + ct * 16 + m] = f2bf(fmaxf(acc[r], 0.f));
    }
    short8 a20 = *(short8*)&tl[m * 80 + q * 8];
    short8 a21 = *(short8*)&tl[m * 80 + 32 + q * 8];
#pragma unroll
    for (int ct = 0; ct < 2; ct++) {
        v4f acc = {0.f, 0.f, 0.f, 0.f};   // pb2 bias pre-written by k_stats
        acc = __builtin_amdgcn_mfma_f32_16x16x32_bf16(a20, bf2[ct][0], acc, 0, 0, 0);
        acc = __builtin_amdgcn_mfma_f32_16x16x32_bf16(a21, bf2[ct][1], acc, 0, 0, 0);
#pragma unroll
        for (int r = 0; r < 4; r++)
            sZ[(w * 16 + q * 4 + r) * 33 + ct * 16 + m] = acc[r];
    }
    __syncthreads();

    if (t < 32) {
        int cur = sGid[0];
        float a = 0.f;
        for (int r = 0; r < 64; r++) {
            int g2 = sGid[r];
            if (g2 != cur) {
                if (cur >= 0) atomicAdd(&out[cur * (NLAYERS * TDIM) + l * TDIM + t], a * inv_safe[cur]);
                cur = g2;
                a = 0.f;
            }
            if (g2 >= 0) a += sZ[r * 33 + t];
        }
        if (cur >= 0) atomicAdd(&out[cur * (NLAYERS * TDIM) + l * TDIM + t], a * inv_safe[cur]);
    }
}

// ---------------- launcher ----------------

extern "C" void kernel_launch(void* const* d_in, const int* in_sizes, int n_in,
                              void* d_out, int out_size, void* d_ws, size_t ws_size,
                              hipStream_t stream) {
    const float* x        = (const float*)d_in[0];
    const int*   src      = (const int*)d_in[1];
    const int*   dst      = (const int*)d_in[2];
    const int*   gid      = (const int*)d_in[3];
    const float* eps      = (const float*)d_in[4];
    const float* conv_w1  = (const float*)d_in[5];
    const float* conv_b1  = (const float*)d_in[6];
    const float* conv_w2  = (const float*)d_in[7];
    const float* conv_b2  = (const float*)d_in[8];
    const float* gn_w     = (const float*)d_in[9];
    const float* gn_b     = (const float*)d_in[10];
    const float* gn_s     = (const float*)d_in[11];
    const float* proj_w1  = (const float*)d_in[12];
    const float* proj_b1  = (const float*)d_in[13];
    const float* proj_w2  = (const float*)d_in[14];
    const float* proj_b2  = (const float*)d_in[15];
    float* out = (float*)d_out;

    char* ws = (char*)d_ws;
    size_t off = 0;
    auto alloc = [&](size_t bytes) { char* p = ws + off; off += (bytes + 255) & ~(size_t)255; return p; };
    int*   offs     = (int*)alloc(NP * sizeof(int));
    int*   gstart   = (int*)alloc((NGRAPH + 1) * sizeof(int));
    float* inv_safe = (float*)alloc(NGRAPH * sizeof(float));
    int*   bcnt     = (int*)alloc(NBUCK * sizeof(int));
    int*   bbase    = (int*)alloc((NBUCK + 1) * sizeof(int));
    int*   bcursor  = (int*)alloc(NBUCK * sizeof(int));
    int*   csr      = (int*)alloc(N_EDGES * sizeof(int));
    bfu*   featbf   = (bfu*)alloc((size_t)N_NODES * DIM * sizeof(bfu));
    bfu*   hinbf    = (bfu*)alloc((size_t)N_NODES * DIM * sizeof(bfu));
    bfu*   hbufbf   = (bfu*)alloc((size_t)N_NODES * DIM * sizeof(bfu));
    float* gms      = (float*)alloc((size_t)NGRAPH * 64 * sizeof(float));
    float* gcoef    = (float*)alloc((size_t)NGRAPH * 64 * sizeof(float));
    bfu*   w1t      = (bfu*)alloc((size_t)NLAYERS * 4096 * sizeof(bfu));
    bfu*   w2t      = (bfu*)alloc((size_t)NLAYERS * 4096 * sizeof(bfu));
    bfu*   p1t      = (bfu*)alloc((size_t)NLAYERS * 4096 * sizeof(bfu));
    bfu*   p2t      = (bfu*)alloc((size_t)NLAYERS * 2048 * sizeof(bfu));
    int2*  ebuf     = (int2*)alloc((size_t)N_EDGES * sizeof(int2));   // setup-only

    // setup
    k_graph_start<<<1, 512, 0, stream>>>(gid, gstart, inv_safe);
    hipMemsetAsync(bcnt, 0, NBUCK * sizeof(int), stream);
    k_bhist<<<256, 256, 0, stream>>>(dst, bcnt);
    k_bscan<<<1, 256, 0, stream>>>(bcnt, bbase, bcursor);
    k_bscatter<<<256, 256, 0, stream>>>(src, dst, bcursor, ebuf);
    k_bcsr<<<NBUCK, 256, 0, stream>>>(ebuf, bbase, offs, csr);
    k_x2bf<<<(N_NODES * DIM / 4) / 256, 256, 0, stream>>>(x, featbf);
    k_wprep<<<48, 256, 0, stream>>>(conv_w1, conv_w2, proj_w1, proj_w2, w1t, w2t, p1t, p2t);

    int aggbl = (N_NODES + 3) / 4;
    int mlpbl = (N_NODES + 63) / 64;
    for (int l = 0; l < NLAYERS; l++) {
        k_agg<<<aggbl, 256, 0, stream>>>(featbf, offs, csr, eps, l, hinbf);
        k_mlp<<<mlpbl, 256, 0, stream>>>(hinbf, w1t + l * 4096, conv_b1 + l * 64,
                                         w2t + l * 4096, conv_b2 + l * 64, hbufbf);
        k_stats<<<NGRAPH, 256, 0, stream>>>(hbufbf, gstart, inv_safe,
                                            gn_w + l * 64, gn_s + l * 64, proj_b2 + l * 32,
                                            gms, gcoef, out, l);
        k_apply_proj<<<mlpbl, 256, 0, stream>>>(hbufbf, gid, gms, gcoef, gn_b + l * 64,
                                                inv_safe, p1t + l * 4096, proj_b1 + l * 64,
                                                p2t + l * 2048, featbf, out, l);
    }
}